// Round 12
// baseline (5118.644 us; speedup 1.0000x reference)
//
#include <hip/hip_runtime.h>
#include <stdint.h>

#define TSTEPS 100
#define BATCH  512
#define NH     256
#define NS     128

__device__ __forceinline__ uint32_t rotl32(uint32_t x, int r) {
  return (x << r) | (x >> (32 - r));
}

// Threefry-2x32-20, exactly as jax/_src/prng.py
__device__ __forceinline__ void tf2x32(uint32_t k0, uint32_t k1,
                                       uint32_t c0, uint32_t c1,
                                       uint32_t& o0, uint32_t& o1) {
  const uint32_t ks2 = k0 ^ k1 ^ 0x1BD11BDAu;
  uint32_t x0 = c0 + k0, x1 = c1 + k1;
#define TFR(r) { x0 += x1; x1 = rotl32(x1, r); x1 ^= x0; }
  TFR(13) TFR(15) TFR(26) TFR(6)
  x0 += k1;  x1 += ks2 + 1u;
  TFR(17) TFR(29) TFR(16) TFR(24)
  x0 += ks2; x1 += k0 + 2u;
  TFR(13) TFR(15) TFR(26) TFR(6)
  x0 += k0;  x1 += k1 + 3u;
  TFR(17) TFR(29) TFR(16) TFR(24)
  x0 += k1;  x1 += ks2 + 4u;
  TFR(13) TFR(15) TFR(26) TFR(6)
  x0 += ks2; x1 += k0 + 5u;
#undef TFR
  o0 = x0; o1 = x1;
}

// XLA:CPU GenerateVF32Log (Cephes port, FMA form). Inputs in (0,1], normal.
__device__ __forceinline__ float xla_vf32_log(float a) {
  uint32_t bits = __float_as_uint(a);
  float e = __fadd_rn((float)((int)(bits >> 23) - 127), 1.0f);
  float x = __uint_as_float((bits & 0x007FFFFFu) | 0x3F000000u);
  const bool mask = x < 0.707106781186547524f;
  float tmp = mask ? x : 0.0f;
  x = __fsub_rn(x, 1.0f);
  e = mask ? __fsub_rn(e, 1.0f) : e;
  x = __fadd_rn(x, tmp);
  float z = __fmul_rn(x, x);
  float y = 7.0376836292e-2f;
  y = __fmaf_rn(y, x, -1.1514610310e-1f);
  y = __fmaf_rn(y, x, 1.1676998740e-1f);
  y = __fmaf_rn(y, x, -1.2420140846e-1f);
  y = __fmaf_rn(y, x, 1.4249322787e-1f);
  y = __fmaf_rn(y, x, -1.6668057665e-1f);
  y = __fmaf_rn(y, x, 2.0000714765e-1f);
  y = __fmaf_rn(y, x, -2.4999993993e-1f);
  y = __fmaf_rn(y, x, 3.3333331174e-1f);
  y = __fmul_rn(y, x);
  y = __fmul_rn(y, z);
  y = __fmaf_rn(e, -2.12194440e-4f, y);
  y = __fmaf_rn(-0.5f, z, y);
  x = __fadd_rn(x, y);
  x = __fmaf_rn(e, 0.693359375f, x);
  return x;
}

// sqrt(2)*erfinv(u): chlo erf_inv f32 (Giles) + EmitLog1p, FMA-contracted.
__device__ __forceinline__ float xla_sqrt2_erfinv(float u) {
  float nxx = -__fmul_rn(u, u);
  float w;
  if (fabsf(nxx) < 1e-4f) {
    w = -__fmul_rn(__fmaf_rn(-0.5f, nxx, 1.0f), nxx);
  } else {
    w = -xla_vf32_log(__fadd_rn(nxx, 1.0f));
  }
  float p;
  if (w < 5.0f) {
    float t = __fsub_rn(w, 2.5f);
    p = 2.81022636e-08f;
    p = __fmaf_rn(p, t, 3.43273939e-07f);
    p = __fmaf_rn(p, t, -3.5233877e-06f);
    p = __fmaf_rn(p, t, -4.39150654e-06f);
    p = __fmaf_rn(p, t, 0.00021858087f);
    p = __fmaf_rn(p, t, -0.00125372503f);
    p = __fmaf_rn(p, t, -0.00417768164f);
    p = __fmaf_rn(p, t, 0.246640727f);
    p = __fmaf_rn(p, t, 1.50140941f);
  } else {
    float t = __fsub_rn(__fsqrt_rn(w), 3.0f);
    p = -0.000200214257f;
    p = __fmaf_rn(p, t, 0.000100950558f);
    p = __fmaf_rn(p, t, 0.00134934322f);
    p = __fmaf_rn(p, t, -0.00367342844f);
    p = __fmaf_rn(p, t, 0.00573950773f);
    p = __fmaf_rn(p, t, -0.0076224613f);
    p = __fmaf_rn(p, t, 0.00943887047f);
    p = __fmaf_rn(p, t, 1.00167406f);
    p = __fmaf_rn(p, t, 2.83297682f);
  }
  return __fmul_rn((float)1.4142135623730951, __fmul_rn(p, u));
}

// jax.random.normal element j under key (k0,k1), threefry-partitionable.
__device__ __forceinline__ float jax_normal(uint32_t k0, uint32_t k1, uint32_t j) {
  uint32_t o0, o1;
  tf2x32(k0, k1, 0u, j, o0, o1);
  const uint32_t bits = o0 ^ o1;
  float f = __fsub_rn(__uint_as_float((bits >> 9) | 0x3f800000u), 1.0f);
  const float LO = -0.99999994f;
  float u = __fmaf_rn(f, 2.0f, LO);
  u = fmaxf(LO, u);
  return xla_sqrt2_erfinv(u);
}

// Pack W[K][256] -> P[k/4][n][4]; optionally zero diagonal (rec masks).
__global__ void pack_w(const float* __restrict__ src, float* __restrict__ dst,
                       int K, int zero_diag) {
  int tid = blockIdx.x * 256 + threadIdx.x;
  if (tid >= K * NH) return;
  int k = tid >> 8, n = tid & 255;
  float v = src[tid];
  if (zero_diag && k == n) v = 0.f;
  dst[(((k >> 2) * NH) + n) * 4 + (k & 3)] = v;
}

// Precompute all scaled noise draws: NZ[((t*5+d)*BATCH+b)*NH+n].
__global__ __launch_bounds__(256)
void gen_noise(float* __restrict__ NZ) {
  uint32_t idx = blockIdx.x * 256u + threadIdx.x;
  uint32_t j = idx & 131071u;          // b*NH + n
  uint32_t td = idx >> 17;             // t*5 + d  (< 500)
  uint32_t t = td / 5u, d = td - 5u * t;
  uint32_t fk0, fk1, k0, k1;
  tf2x32(0u, 42u, 0u, t, fk0, fk1);
  tf2x32(fk0, fk1, 0u, d, k0, k1);
  float z = jax_normal(k0, k1, j);
  float scale = (d >= 3u) ? 0.01f : 0.02f;
  NZ[idx] = __fmul_rn(scale, z);
}

// ============ dense k-ascending dot segments (verified R6 chains) ============
__device__ __forceinline__ void dot1_seg(const float4* __restrict__ P0,
                                         const float* __restrict__ A0,
                                         int n, int k4b, int k4e, float& r0) {
  float a0 = r0;
  #pragma unroll 8
  for (int k4 = k4b; k4 < k4e; ++k4) {
    float4 w0 = P0[k4 * NH + n];
    float4 x0 = *reinterpret_cast<const float4*>(A0 + 4 * k4);
    a0 = __fmaf_rn(x0.x, w0.x, a0); a0 = __fmaf_rn(x0.y, w0.y, a0);
    a0 = __fmaf_rn(x0.z, w0.z, a0); a0 = __fmaf_rn(x0.w, w0.w, a0);
  }
  r0 = a0;
}

__device__ __forceinline__ void dot2_seg(const float4* __restrict__ P0,
                                         const float* __restrict__ A0,
                                         const float4* __restrict__ P1,
                                         const float* __restrict__ A1,
                                         int n, int k4b, int k4e,
                                         float& r0, float& r1) {
  float a0 = r0, a1 = r1;
  #pragma unroll 8
  for (int k4 = k4b; k4 < k4e; ++k4) {
    float4 w0 = P0[k4 * NH + n];
    float4 w1 = P1[k4 * NH + n];
    float4 x0 = *reinterpret_cast<const float4*>(A0 + 4 * k4);
    float4 x1 = *reinterpret_cast<const float4*>(A1 + 4 * k4);
    a0 = __fmaf_rn(x0.x, w0.x, a0); a0 = __fmaf_rn(x0.y, w0.y, a0);
    a0 = __fmaf_rn(x0.z, w0.z, a0); a0 = __fmaf_rn(x0.w, w0.w, a0);
    a1 = __fmaf_rn(x1.x, w1.x, a1); a1 = __fmaf_rn(x1.y, w1.y, a1);
    a1 = __fmaf_rn(x1.z, w1.z, a1); a1 = __fmaf_rn(x1.w, w1.w, a1);
  }
  r0 = a0; r1 = a1;
}

// Sparse p2r dot: skip k4 quads where all 4 spike inputs are zero.
// fma(0,w,acc)==acc exactly; quad order ascending -> bit-exact vs dense.
// Spike values in {0,1}: sum !=0 iff any active. Branch is wave-uniform
// (all lanes read the same psp quad).
__device__ __forceinline__ float dot_sparse(const float4* __restrict__ P,
                                            const float* __restrict__ S,
                                            int n) {
  float acc = 0.f;
  for (int k4 = 0; k4 < 64; ++k4) {
    float4 s = *reinterpret_cast<const float4*>(S + 4 * k4);
    if (__fadd_rn(__fadd_rn(s.x, s.y), __fadd_rn(s.z, s.w)) != 0.f) {
      float4 w = P[k4 * NH + n];
      acc = __fmaf_rn(s.x, w.x, acc); acc = __fmaf_rn(s.y, w.y, acc);
      acc = __fmaf_rn(s.z, w.z, acc); acc = __fmaf_rn(s.w, w.w, acc);
    }
  }
  return acc;
}

// ============ main: R6 champion structure + p2r quad-skip ============
__global__ __launch_bounds__(NH)
void wm_fast6(const float* __restrict__ sensory,
              const float4* __restrict__ pred0p, const float4* __restrict__ pred1p,
              const float4* __restrict__ p2r0p,  const float4* __restrict__ rec0p,
              const float4* __restrict__ ff0p,   const float4* __restrict__ p2r1p,
              const float4* __restrict__ ff1p,   const float4* __restrict__ rec1p,
              const float4* __restrict__ ff2p,   const float4* __restrict__ rec2p,
              const float* __restrict__ NZ,
              float* __restrict__ out) {
  const int b = blockIdx.x;
  const int n = threadIdx.x;

  __shared__ __align__(16) float last[2][3][NH];
  __shared__ __align__(16) float psp0[NH];
  __shared__ __align__(16) float psp1[NH];
  __shared__ __align__(16) float sens[NS];
  __shared__ __align__(16) float errsq[3][NH];
  __shared__ float evsum[3];

  for (int i = 0; i < 3; ++i) { last[0][i][n] = 0.f; last[1][i][n] = 0.f; }

  float v0 = 0.f, v1 = 0.f, v2 = 0.f, pv0 = 0.f, pv1 = 0.f;
  float prec0 = 1.f, prec1 = 1.f, prec2 = 1.f;
  const float DM = (float)0.951229424500714009;  // f32(exp(-1/20))
  const float DP = (float)0.980198673306755250;  // f32(exp(-1/50))

  __syncthreads();

  for (int t = 0; t < TSTEPS; ++t) {
    const int p = t & 1, q = p ^ 1;
    const size_t nb = ((size_t)t * 5 * BATCH + b) * NH + n;  // draw 0 offset

    // ---- A: fused pred-LIF 0 & 1 (dense; repr spike rate too high to skip) --
    if (n < NS) sens[n] = sensory[((size_t)t * BATCH + b) * NS + n];
    {
      float pn0 = NZ[nb + (size_t)3 * BATCH * NH];
      float pn1 = NZ[nb + (size_t)4 * BATCH * NH];
      float acc0 = 0.f, acc1 = 0.f;
      dot2_seg(pred0p, last[p][1], pred1p, last[p][2], n, 0, 64, acc0, acc1);
      pv0 = __fadd_rn(__fmaf_rn(DP, pv0, acc0), pn0);
      bool s0 = (pv0 >= 1.0f);
      psp0[n] = s0 ? 1.f : 0.f;
      pv0 = s0 ? 0.f : pv0;
      pv1 = __fadd_rn(__fmaf_rn(DP, pv1, acc1), pn1);
      bool s1 = (pv1 >= 1.0f);
      psp1[n] = s1 ? 1.f : 0.f;
      pv1 = s1 ? 0.f : pv1;
    }
    __syncthreads();

    // ---- B: layer 0 (dense ff0+rec0 pipelined; sparse p2r0) ----
    {
      float noi = NZ[nb];
      float inp = 0.f, rc = 0.f;
      dot2_seg(ff0p, sens, rec0p, last[p][0], n, 0, 32, inp, rc);
      dot1_seg(rec0p, last[p][0], n, 32, 64, rc);
      float pr = dot_sparse(p2r0p, psp0, n);
      float err = __fsub_rn(inp, pr);
      out[(((size_t)t * 3 + 0) * BATCH + b) * NH + n] = err;
      errsq[0][n] = __fmul_rn(err, err);
      float m1  = __fmul_rn(err, 0.5f);
      float tot = __fadd_rn(__fmaf_rn(m1, prec0, pr), rc);
      v0 = __fadd_rn(__fmaf_rn(DM, v0, tot), noi);
      bool s = (v0 >= 1.0f);
      last[q][0][n] = s ? 1.f : 0.f;
      v0 = s ? 0.f : v0;
    }
    __syncthreads();

    // ---- D: layer 1 (dense ff1+rec1 pipelined; sparse p2r1) ----
    {
      float noi = NZ[nb + (size_t)1 * BATCH * NH];
      float inp = 0.f, rc = 0.f;
      dot2_seg(ff1p, last[q][0], rec1p, last[p][1], n, 0, 64, inp, rc);
      float pr = dot_sparse(p2r1p, psp1, n);
      float err = __fsub_rn(inp, pr);
      out[(((size_t)t * 3 + 1) * BATCH + b) * NH + n] = err;
      errsq[1][n] = __fmul_rn(err, err);
      float m1  = __fmul_rn(err, 0.5f);
      float tot = __fadd_rn(__fmaf_rn(m1, prec1, pr), rc);
      v1 = __fadd_rn(__fmaf_rn(DM, v1, tot), noi);
      bool s = (v1 >= 1.0f);
      last[q][1][n] = s ? 1.f : 0.f;
      v1 = s ? 0.f : v1;
    }
    __syncthreads();

    // ---- E: layer 2 (dense; no prediction) ----
    {
      float noi = NZ[nb + (size_t)2 * BATCH * NH];
      float inp = 0.f, rc = 0.f;
      dot2_seg(ff2p, last[q][1], rec2p, last[p][2], n, 0, 64, inp, rc);
      float err = inp;
      out[(((size_t)t * 3 + 2) * BATCH + b) * NH + n] = err;
      errsq[2][n] = __fmul_rn(err, err);
      float m1  = __fmul_rn(err, 0.5f);
      float tot = __fadd_rn(__fmaf_rn(m1, prec2, 0.0f), rc);
      v2 = __fadd_rn(__fmaf_rn(DM, v2, tot), noi);
      bool s = (v2 >= 1.0f);
      last[q][2][n] = s ? 1.f : 0.f;
      v2 = s ? 0.f : v2;
    }
    __syncthreads();

    // ---- F: strict sequential err^2 sums (lane 0 of waves 0..2) ----
    if (((n & 63) == 0) && n < 192) {
      const float4* s4 = reinterpret_cast<const float4*>(errsq[n >> 6]);
      float acc = 0.f;
      #pragma unroll 16
      for (int k4 = 0; k4 < 64; ++k4) {
        float4 v = s4[k4];
        acc = __fadd_rn(acc, v.x); acc = __fadd_rn(acc, v.y);
        acc = __fadd_rn(acc, v.z); acc = __fadd_rn(acc, v.w);
      }
      evsum[n >> 6] = acc;
    }
    __syncthreads();

    // ---- G: precision EMA ----
    {
      float ev0 = __fadd_rn(__fmul_rn(evsum[0], 0.00390625f), 1e-6f);
      float ev1 = __fadd_rn(__fmul_rn(evsum[1], 0.00390625f), 1e-6f);
      float ev2 = __fadd_rn(__fmul_rn(evsum[2], 0.00390625f), 1e-6f);
      prec0 = __fmaf_rn(0.98f, prec0, __fmul_rn(0.02f, 1.0f / ev0));
      prec1 = __fmaf_rn(0.98f, prec1, __fmul_rn(0.02f, 1.0f / ev1));
      prec2 = __fmaf_rn(0.98f, prec2, __fmul_rn(0.02f, 1.0f / ev2));
    }
  }
}

// ======================= fallback (verified R5 kernel) =======================
__device__ __forceinline__ float dot_lds(const float* __restrict__ a,
                                         const float* __restrict__ W,
                                         int n, int K) {
  float acc = 0.f;
  #pragma unroll 8
  for (int k = 0; k < K; ++k)
    acc = __fmaf_rn(a[k], W[k * NH + n], acc);
  return acc;
}

__device__ __forceinline__ float dot_rec(const float* __restrict__ a,
                                         const float* __restrict__ W, int n) {
  float acc = 0.f;
  #pragma unroll 8
  for (int k = 0; k < NH; ++k) {
    float w = (k == n) ? 0.f : W[k * NH + n];
    acc = __fmaf_rn(a[k], w, acc);
  }
  return acc;
}

__global__ __launch_bounds__(NH)
void wm_kernel_mono(const float* __restrict__ sensory,
                    const float* __restrict__ ff0, const float* __restrict__ ff1,
                    const float* __restrict__ ff2,
                    const float* __restrict__ rec0, const float* __restrict__ rec1,
                    const float* __restrict__ rec2,
                    const float* __restrict__ pred0, const float* __restrict__ pred1,
                    const float* __restrict__ p2r0, const float* __restrict__ p2r1,
                    float* __restrict__ out) {
  const int b = blockIdx.x;
  const int n = threadIdx.x;

  __shared__ float last[2][3][NH];
  __shared__ float psp[NH];
  __shared__ float sens[NS];
  __shared__ float errsq[3][NH];
  __shared__ float evsum[3];
  __shared__ uint32_t keys[TSTEPS][5][2];

  if (n < TSTEPS) {
    uint32_t fk0, fk1;
    tf2x32(0u, 42u, 0u, (uint32_t)n, fk0, fk1);
    #pragma unroll
    for (int i = 0; i < 5; ++i) {
      uint32_t s0, s1;
      tf2x32(fk0, fk1, 0u, (uint32_t)i, s0, s1);
      keys[n][i][0] = s0; keys[n][i][1] = s1;
    }
  }
  for (int i = 0; i < 3; ++i) { last[0][i][n] = 0.f; last[1][i][n] = 0.f; }

  float v0 = 0.f, v1 = 0.f, v2 = 0.f, pv0 = 0.f, pv1 = 0.f;
  float prec0 = 1.f, prec1 = 1.f, prec2 = 1.f;
  const float DM = (float)0.951229424500714009;
  const float DP = (float)0.980198673306755250;
  const uint32_t j = (uint32_t)(b * NH + n);

  __syncthreads();

  for (int t = 0; t < TSTEPS; ++t) {
    const int p = t & 1, q = p ^ 1;

    if (n < NS) sens[n] = sensory[((size_t)t * BATCH + b) * NS + n];
    {
      float acc = dot_lds(last[p][1], pred0, n, NH);
      float pn = __fmul_rn(0.01f, jax_normal(keys[t][3][0], keys[t][3][1], j));
      pv0 = __fadd_rn(__fmaf_rn(DP, pv0, acc), pn);
      bool s = (pv0 >= 1.0f);
      psp[n] = s ? 1.f : 0.f;
      pv0 = s ? 0.f : pv0;
    }
    __syncthreads();

    {
      float pr  = dot_lds(psp, p2r0, n, NH);
      float inp = dot_lds(sens, ff0, n, NS);
      float rc  = dot_rec(last[p][0], rec0, n);
      float err = __fsub_rn(inp, pr);
      out[(((size_t)t * 3 + 0) * BATCH + b) * NH + n] = err;
      errsq[0][n] = __fmul_rn(err, err);
      float m1  = __fmul_rn(err, 0.5f);
      float tot = __fadd_rn(__fmaf_rn(m1, prec0, pr), rc);
      float noi = __fmul_rn(0.02f, jax_normal(keys[t][0][0], keys[t][0][1], j));
      v0 = __fadd_rn(__fmaf_rn(DM, v0, tot), noi);
      bool s = (v0 >= 1.0f);
      last[q][0][n] = s ? 1.f : 0.f;
      v0 = s ? 0.f : v0;
    }
    __syncthreads();

    {
      float acc = dot_lds(last[p][2], pred1, n, NH);
      float pn = __fmul_rn(0.01f, jax_normal(keys[t][4][0], keys[t][4][1], j));
      pv1 = __fadd_rn(__fmaf_rn(DP, pv1, acc), pn);
      bool s = (pv1 >= 1.0f);
      psp[n] = s ? 1.f : 0.f;
      pv1 = s ? 0.f : pv1;
    }
    __syncthreads();

    {
      float pr  = dot_lds(psp, p2r1, n, NH);
      float inp = dot_lds(last[q][0], ff1, n, NH);
      float rc  = dot_rec(last[p][1], rec1, n);
      float err = __fsub_rn(inp, pr);
      out[(((size_t)t * 3 + 1) * BATCH + b) * NH + n] = err;
      errsq[1][n] = __fmul_rn(err, err);
      float m1  = __fmul_rn(err, 0.5f);
      float tot = __fadd_rn(__fmaf_rn(m1, prec1, pr), rc);
      float noi = __fmul_rn(0.02f, jax_normal(keys[t][1][0], keys[t][1][1], j));
      v1 = __fadd_rn(__fmaf_rn(DM, v1, tot), noi);
      bool s = (v1 >= 1.0f);
      last[q][1][n] = s ? 1.f : 0.f;
      v1 = s ? 0.f : v1;
    }
    __syncthreads();

    {
      float inp = dot_lds(last[q][1], ff2, n, NH);
      float rc  = dot_rec(last[p][2], rec2, n);
      float err = inp;
      out[(((size_t)t * 3 + 2) * BATCH + b) * NH + n] = err;
      errsq[2][n] = __fmul_rn(err, err);
      float m1  = __fmul_rn(err, 0.5f);
      float tot = __fadd_rn(__fmaf_rn(m1, prec2, 0.0f), rc);
      float noi = __fmul_rn(0.02f, jax_normal(keys[t][2][0], keys[t][2][1], j));
      v2 = __fadd_rn(__fmaf_rn(DM, v2, tot), noi);
      bool s = (v2 >= 1.0f);
      last[q][2][n] = s ? 1.f : 0.f;
      v2 = s ? 0.f : v2;
    }
    __syncthreads();

    if (((n & 63) == 0) && n < 192) {
      const float* s = errsq[n >> 6];
      float acc = 0.f;
      #pragma unroll 32
      for (int k = 0; k < NH; ++k) acc = __fadd_rn(acc, s[k]);
      evsum[n >> 6] = acc;
    }
    __syncthreads();

    {
      float ev0 = __fadd_rn(__fmul_rn(evsum[0], 0.00390625f), 1e-6f);
      float ev1 = __fadd_rn(__fmul_rn(evsum[1], 0.00390625f), 1e-6f);
      float ev2 = __fadd_rn(__fmul_rn(evsum[2], 0.00390625f), 1e-6f);
      prec0 = __fmaf_rn(0.98f, prec0, __fmul_rn(0.02f, 1.0f / ev0));
      prec1 = __fmaf_rn(0.98f, prec1, __fmul_rn(0.02f, 1.0f / ev1));
      prec2 = __fmaf_rn(0.98f, prec2, __fmul_rn(0.02f, 1.0f / ev2));
    }
  }
}

extern "C" void kernel_launch(void* const* d_in, const int* in_sizes, int n_in,
                              void* d_out, int out_size, void* d_ws, size_t ws_size,
                              hipStream_t stream) {
  (void)in_sizes; (void)n_in; (void)out_size;
  const float* sensory = (const float*)d_in[0];
  const float* ff0  = (const float*)d_in[1];
  const float* ff1  = (const float*)d_in[2];
  const float* ff2  = (const float*)d_in[3];
  const float* rec0 = (const float*)d_in[4];
  const float* rec1 = (const float*)d_in[5];
  const float* rec2 = (const float*)d_in[6];
  const float* pred0 = (const float*)d_in[7];
  const float* pred1 = (const float*)d_in[8];
  const float* p2r0 = (const float*)d_in[9];
  const float* p2r1 = (const float*)d_in[10];
  float* out = (float*)d_out;

  // ws layout (floats): packed weights then noise.
  const size_t OFF_PRED0 = 0, OFF_PRED1 = 65536, OFF_P2R0 = 131072,
               OFF_REC0 = 196608, OFF_FF0 = 262144, OFF_P2R1 = 294912,
               OFF_FF1 = 360448, OFF_REC1 = 425984, OFF_FF2 = 491520,
               OFF_REC2 = 557056, OFF_NZ = 655360;
  const size_t NZ_FLOATS = (size_t)TSTEPS * 5 * BATCH * NH;  // 65,536,000
  const size_t NEED = (OFF_NZ + NZ_FLOATS) * sizeof(float);

  if (ws_size >= NEED) {
    float* W = (float*)d_ws;
    pack_w<<<dim3(NH * NH / 256), dim3(256), 0, stream>>>(pred0, W + OFF_PRED0, NH, 0);
    pack_w<<<dim3(NH * NH / 256), dim3(256), 0, stream>>>(pred1, W + OFF_PRED1, NH, 0);
    pack_w<<<dim3(NH * NH / 256), dim3(256), 0, stream>>>(p2r0,  W + OFF_P2R0,  NH, 0);
    pack_w<<<dim3(NH * NH / 256), dim3(256), 0, stream>>>(rec0,  W + OFF_REC0,  NH, 1);
    pack_w<<<dim3(NS * NH / 256), dim3(256), 0, stream>>>(ff0,   W + OFF_FF0,   NS, 0);
    pack_w<<<dim3(NH * NH / 256), dim3(256), 0, stream>>>(p2r1,  W + OFF_P2R1,  NH, 0);
    pack_w<<<dim3(NH * NH / 256), dim3(256), 0, stream>>>(ff1,   W + OFF_FF1,   NH, 0);
    pack_w<<<dim3(NH * NH / 256), dim3(256), 0, stream>>>(rec1,  W + OFF_REC1,  NH, 1);
    pack_w<<<dim3(NH * NH / 256), dim3(256), 0, stream>>>(ff2,   W + OFF_FF2,   NH, 0);
    pack_w<<<dim3(NH * NH / 256), dim3(256), 0, stream>>>(rec2,  W + OFF_REC2,  NH, 1);
    gen_noise<<<dim3((unsigned)(NZ_FLOATS / 256)), dim3(256), 0, stream>>>(W + OFF_NZ);
    wm_fast6<<<dim3(BATCH), dim3(NH), 0, stream>>>(
        sensory,
        (const float4*)(W + OFF_PRED0), (const float4*)(W + OFF_PRED1),
        (const float4*)(W + OFF_P2R0),  (const float4*)(W + OFF_REC0),
        (const float4*)(W + OFF_FF0),   (const float4*)(W + OFF_P2R1),
        (const float4*)(W + OFF_FF1),   (const float4*)(W + OFF_REC1),
        (const float4*)(W + OFF_FF2),   (const float4*)(W + OFF_REC2),
        W + OFF_NZ, out);
  } else {
    wm_kernel_mono<<<dim3(BATCH), dim3(NH), 0, stream>>>(
        sensory, ff0, ff1, ff2, rec0, rec1, rec2,
        pred0, pred1, p2r0, p2r1, out);
  }
}

// Round 14
// 4525.499 us; speedup vs baseline: 1.1311x; 1.1311x over previous
//
#include <hip/hip_runtime.h>
#include <stdint.h>

#define TSTEPS 100
#define BATCH  512
#define NH     256
#define NS     128

__device__ __forceinline__ uint32_t rotl32(uint32_t x, int r) {
  return (x << r) | (x >> (32 - r));
}

// Threefry-2x32-20, exactly as jax/_src/prng.py
__device__ __forceinline__ void tf2x32(uint32_t k0, uint32_t k1,
                                       uint32_t c0, uint32_t c1,
                                       uint32_t& o0, uint32_t& o1) {
  const uint32_t ks2 = k0 ^ k1 ^ 0x1BD11BDAu;
  uint32_t x0 = c0 + k0, x1 = c1 + k1;
#define TFR(r) { x0 += x1; x1 = rotl32(x1, r); x1 ^= x0; }
  TFR(13) TFR(15) TFR(26) TFR(6)
  x0 += k1;  x1 += ks2 + 1u;
  TFR(17) TFR(29) TFR(16) TFR(24)
  x0 += ks2; x1 += k0 + 2u;
  TFR(13) TFR(15) TFR(26) TFR(6)
  x0 += k0;  x1 += k1 + 3u;
  TFR(17) TFR(29) TFR(16) TFR(24)
  x0 += k1;  x1 += ks2 + 4u;
  TFR(13) TFR(15) TFR(26) TFR(6)
  x0 += ks2; x1 += k0 + 5u;
#undef TFR
  o0 = x0; o1 = x1;
}

// XLA:CPU GenerateVF32Log (Cephes port, FMA form). Inputs in (0,1], normal.
__device__ __forceinline__ float xla_vf32_log(float a) {
  uint32_t bits = __float_as_uint(a);
  float e = __fadd_rn((float)((int)(bits >> 23) - 127), 1.0f);
  float x = __uint_as_float((bits & 0x007FFFFFu) | 0x3F000000u);
  const bool mask = x < 0.707106781186547524f;
  float tmp = mask ? x : 0.0f;
  x = __fsub_rn(x, 1.0f);
  e = mask ? __fsub_rn(e, 1.0f) : e;
  x = __fadd_rn(x, tmp);
  float z = __fmul_rn(x, x);
  float y = 7.0376836292e-2f;
  y = __fmaf_rn(y, x, -1.1514610310e-1f);
  y = __fmaf_rn(y, x, 1.1676998740e-1f);
  y = __fmaf_rn(y, x, -1.2420140846e-1f);
  y = __fmaf_rn(y, x, 1.4249322787e-1f);
  y = __fmaf_rn(y, x, -1.6668057665e-1f);
  y = __fmaf_rn(y, x, 2.0000714765e-1f);
  y = __fmaf_rn(y, x, -2.4999993993e-1f);
  y = __fmaf_rn(y, x, 3.3333331174e-1f);
  y = __fmul_rn(y, x);
  y = __fmul_rn(y, z);
  y = __fmaf_rn(e, -2.12194440e-4f, y);
  y = __fmaf_rn(-0.5f, z, y);
  x = __fadd_rn(x, y);
  x = __fmaf_rn(e, 0.693359375f, x);
  return x;
}

// sqrt(2)*erfinv(u): chlo erf_inv f32 (Giles) + EmitLog1p, FMA-contracted.
__device__ __forceinline__ float xla_sqrt2_erfinv(float u) {
  float nxx = -__fmul_rn(u, u);
  float w;
  if (fabsf(nxx) < 1e-4f) {
    w = -__fmul_rn(__fmaf_rn(-0.5f, nxx, 1.0f), nxx);
  } else {
    w = -xla_vf32_log(__fadd_rn(nxx, 1.0f));
  }
  float p;
  if (w < 5.0f) {
    float t = __fsub_rn(w, 2.5f);
    p = 2.81022636e-08f;
    p = __fmaf_rn(p, t, 3.43273939e-07f);
    p = __fmaf_rn(p, t, -3.5233877e-06f);
    p = __fmaf_rn(p, t, -4.39150654e-06f);
    p = __fmaf_rn(p, t, 0.00021858087f);
    p = __fmaf_rn(p, t, -0.00125372503f);
    p = __fmaf_rn(p, t, -0.00417768164f);
    p = __fmaf_rn(p, t, 0.246640727f);
    p = __fmaf_rn(p, t, 1.50140941f);
  } else {
    float t = __fsub_rn(__fsqrt_rn(w), 3.0f);
    p = -0.000200214257f;
    p = __fmaf_rn(p, t, 0.000100950558f);
    p = __fmaf_rn(p, t, 0.00134934322f);
    p = __fmaf_rn(p, t, -0.00367342844f);
    p = __fmaf_rn(p, t, 0.00573950773f);
    p = __fmaf_rn(p, t, -0.0076224613f);
    p = __fmaf_rn(p, t, 0.00943887047f);
    p = __fmaf_rn(p, t, 1.00167406f);
    p = __fmaf_rn(p, t, 2.83297682f);
  }
  return __fmul_rn((float)1.4142135623730951, __fmul_rn(p, u));
}

// jax.random.normal element j under key (k0,k1), threefry-partitionable.
__device__ __forceinline__ float jax_normal(uint32_t k0, uint32_t k1, uint32_t j) {
  uint32_t o0, o1;
  tf2x32(k0, k1, 0u, j, o0, o1);
  const uint32_t bits = o0 ^ o1;
  float f = __fsub_rn(__uint_as_float((bits >> 9) | 0x3f800000u), 1.0f);
  const float LO = -0.99999994f;
  float u = __fmaf_rn(f, 2.0f, LO);
  u = fmaxf(LO, u);
  return xla_sqrt2_erfinv(u);
}

// Pack W[K][256] -> P[k/4][n][4]; optionally zero diagonal (rec masks).
__global__ void pack_w(const float* __restrict__ src, float* __restrict__ dst,
                       int K, int zero_diag) {
  int tid = blockIdx.x * 256 + threadIdx.x;
  if (tid >= K * NH) return;
  int k = tid >> 8, n = tid & 255;
  float v = src[tid];
  if (zero_diag && k == n) v = 0.f;
  dst[(((k >> 2) * NH) + n) * 4 + (k & 3)] = v;
}

// Precompute all scaled noise draws: NZ[((t*5+d)*BATCH+b)*NH+n].
__global__ __launch_bounds__(256)
void gen_noise(float* __restrict__ NZ) {
  uint32_t idx = blockIdx.x * 256u + threadIdx.x;
  uint32_t j = idx & 131071u;          // b*NH + n
  uint32_t td = idx >> 17;             // t*5 + d  (< 500)
  uint32_t t = td / 5u, d = td - 5u * t;
  uint32_t fk0, fk1, k0, k1;
  tf2x32(0u, 42u, 0u, t, fk0, fk1);
  tf2x32(fk0, fk1, 0u, d, k0, k1);
  float z = jax_normal(k0, k1, j);
  float scale = (d >= 3u) ? 0.01f : 0.02f;
  NZ[idx] = __fmul_rn(scale, z);
}

// ===== dots: one weight load feeds TWO rows; per-row chains are verbatim
// R6 k-ascending fma chains -> bit-exact. =====
__device__ __forceinline__ void dotW2r(const float4* __restrict__ P,
                                       const float* __restrict__ X0,
                                       const float* __restrict__ X1,
                                       int n, int k4b, int k4e,
                                       float& r0, float& r1) {
  float a0 = r0, a1 = r1;
  #pragma unroll 8
  for (int k4 = k4b; k4 < k4e; ++k4) {
    float4 w = P[k4 * NH + n];
    float4 x0 = *(const float4*)(X0 + 4 * k4);
    float4 x1 = *(const float4*)(X1 + 4 * k4);
    a0 = __fmaf_rn(x0.x, w.x, a0); a1 = __fmaf_rn(x1.x, w.x, a1);
    a0 = __fmaf_rn(x0.y, w.y, a0); a1 = __fmaf_rn(x1.y, w.y, a1);
    a0 = __fmaf_rn(x0.z, w.z, a0); a1 = __fmaf_rn(x1.z, w.z, a1);
    a0 = __fmaf_rn(x0.w, w.w, a0); a1 = __fmaf_rn(x1.w, w.w, a1);
  }
  r0 = a0; r1 = a1;
}

__device__ __forceinline__ void dot2W2r(const float4* __restrict__ PA,
                                        const float* __restrict__ XA0,
                                        const float* __restrict__ XA1,
                                        const float4* __restrict__ PB,
                                        const float* __restrict__ XB0,
                                        const float* __restrict__ XB1,
                                        int n, int k4b, int k4e,
                                        float& rA0, float& rA1,
                                        float& rB0, float& rB1) {
  float a0 = rA0, a1 = rA1, b0 = rB0, b1 = rB1;
  #pragma unroll 4
  for (int k4 = k4b; k4 < k4e; ++k4) {
    float4 wa = PA[k4 * NH + n];
    float4 wb = PB[k4 * NH + n];
    float4 xa0 = *(const float4*)(XA0 + 4 * k4);
    float4 xa1 = *(const float4*)(XA1 + 4 * k4);
    float4 xb0 = *(const float4*)(XB0 + 4 * k4);
    float4 xb1 = *(const float4*)(XB1 + 4 * k4);
    a0 = __fmaf_rn(xa0.x, wa.x, a0); a1 = __fmaf_rn(xa1.x, wa.x, a1);
    b0 = __fmaf_rn(xb0.x, wb.x, b0); b1 = __fmaf_rn(xb1.x, wb.x, b1);
    a0 = __fmaf_rn(xa0.y, wa.y, a0); a1 = __fmaf_rn(xa1.y, wa.y, a1);
    b0 = __fmaf_rn(xb0.y, wb.y, b0); b1 = __fmaf_rn(xb1.y, wb.y, b1);
    a0 = __fmaf_rn(xa0.z, wa.z, a0); a1 = __fmaf_rn(xa1.z, wa.z, a1);
    b0 = __fmaf_rn(xb0.z, wb.z, b0); b1 = __fmaf_rn(xb1.z, wb.z, b1);
    a0 = __fmaf_rn(xa0.w, wa.w, a0); a1 = __fmaf_rn(xa1.w, wa.w, a1);
    b0 = __fmaf_rn(xb0.w, wb.w, b0); b1 = __fmaf_rn(xb1.w, wb.w, b1);
  }
  rA0 = a0; rA1 = a1; rB0 = b0; rB1 = b1;
}

// ===== main: 2 rows/thread (half the weight-load instructions) x chain-split
// (keeps 8 waves/CU). 256 blocks x 512 threads; h=tid>>8 picks chain subset;
// each thread computes its chains for BOTH rows. Bit-exact per-row chains. =====
__global__ __launch_bounds__(512)
void wm_fast7(const float* __restrict__ sensory,
              const float4* __restrict__ pred0p, const float4* __restrict__ pred1p,
              const float4* __restrict__ p2r0p,  const float4* __restrict__ rec0p,
              const float4* __restrict__ ff0p,   const float4* __restrict__ p2r1p,
              const float4* __restrict__ ff1p,   const float4* __restrict__ rec1p,
              const float4* __restrict__ ff2p,   const float4* __restrict__ rec2p,
              const float* __restrict__ NZ,
              float* __restrict__ out) {
  const int tid = threadIdx.x;
  const int n = tid & 255;         // neuron
  const int h = tid >> 8;          // chain-subset selector (wave-uniform)
  const int b0 = blockIdx.x * 2, b1 = b0 + 1;

  __shared__ __align__(16) float last[2][3][2][NH];  // [pp][layer][row][n]
  __shared__ __align__(16) float psp0[2][NH];
  __shared__ __align__(16) float psp1[2][NH];
  __shared__ __align__(16) float sens[2][NS];
  __shared__ __align__(16) float errsq[3][2][NH];
  __shared__ __align__(16) float xfer[2][NH];
  __shared__ float evsum[3][2];

  if (h == 0) {
    #pragma unroll
    for (int i = 0; i < 3; ++i) {
      last[0][i][0][n] = 0.f; last[0][i][1][n] = 0.f;
      last[1][i][0][n] = 0.f; last[1][i][1][n] = 0.f;
    }
  }

  // h=0 owns: pred0-v, layer0-v, layer2-v (x2 rows). h=1: pred1-v, layer1-v.
  float pvR0 = 0.f, pvR1 = 0.f;
  float vX0 = 0.f, vX1 = 0.f;      // layer0 (h=0) / layer1 (h=1)
  float vY0 = 0.f, vY1 = 0.f;      // layer2 (h=0 only)
  float p0a = 1.f, p0b = 1.f, p1a = 1.f, p1b = 1.f, p2a = 1.f, p2b = 1.f;
  const float DM = (float)0.951229424500714009;  // f32(exp(-1/20))
  const float DP = (float)0.980198673306755250;  // f32(exp(-1/50))

  __syncthreads();

  for (int t = 0; t < TSTEPS; ++t) {
    const int p = t & 1, q = p ^ 1;
    const size_t t5 = (size_t)t * 5 * BATCH * NH;
#define NZI(d, bb) (t5 + ((size_t)(d) * BATCH + (bb)) * NH + n)

    // ---- A: pred-LIF 0 (h=0) / pred-LIF 1 (h=1), both rows ----
    if (tid < 2 * NS) {
      int rr = tid >> 7, kk = tid & 127;
      sens[rr][kk] = sensory[((size_t)t * BATCH + b0 + rr) * NS + kk];
    }
    if (h == 0) {
      float a0 = 0.f, a1 = 0.f;
      dotW2r(pred0p, last[p][1][0], last[p][1][1], n, 0, 64, a0, a1);
      float pn0 = NZ[NZI(3, b0)], pn1 = NZ[NZI(3, b1)];
      pvR0 = __fadd_rn(__fmaf_rn(DP, pvR0, a0), pn0);
      bool s0 = (pvR0 >= 1.0f);
      psp0[0][n] = s0 ? 1.f : 0.f;
      pvR0 = s0 ? 0.f : pvR0;
      pvR1 = __fadd_rn(__fmaf_rn(DP, pvR1, a1), pn1);
      bool s1 = (pvR1 >= 1.0f);
      psp0[1][n] = s1 ? 1.f : 0.f;
      pvR1 = s1 ? 0.f : pvR1;
    } else {
      float a0 = 0.f, a1 = 0.f;
      dotW2r(pred1p, last[p][2][0], last[p][2][1], n, 0, 64, a0, a1);
      float pn0 = NZ[NZI(4, b0)], pn1 = NZ[NZI(4, b1)];
      pvR0 = __fadd_rn(__fmaf_rn(DP, pvR0, a0), pn0);
      bool s0 = (pvR0 >= 1.0f);
      psp1[0][n] = s0 ? 1.f : 0.f;
      pvR0 = s0 ? 0.f : pvR0;
      pvR1 = __fadd_rn(__fmaf_rn(DP, pvR1, a1), pn1);
      bool s1 = (pvR1 >= 1.0f);
      psp1[1][n] = s1 ? 1.f : 0.f;
      pvR1 = s1 ? 0.f : pvR1;
    }
    __syncthreads();   // A-end: psp0, psp1, sens ready

    // ---- B: layer 0.  h=0: inp(ff0)+rc(rec0); h=1: pr(p2r0) -> xfer ----
    float sA0 = 0.f, sA1 = 0.f, sB0 = 0.f, sB1 = 0.f;  // phase-local stashes
    if (h == 0) {
      dot2W2r(ff0p, sens[0], sens[1], rec0p, last[p][0][0], last[p][0][1],
              n, 0, 32, sA0, sA1, sB0, sB1);
      dotW2r(rec0p, last[p][0][0], last[p][0][1], n, 32, 64, sB0, sB1);
    } else {
      float pr0 = 0.f, pr1 = 0.f;
      dotW2r(p2r0p, psp0[0], psp0[1], n, 0, 64, pr0, pr1);
      xfer[0][n] = pr0; xfer[1][n] = pr1;
    }
    __syncthreads();   // B-mid: pr available
    if (h == 0) {
      float pr0 = xfer[0][n], pr1 = xfer[1][n];
      float noi0 = NZ[NZI(0, b0)], noi1 = NZ[NZI(0, b1)];
      float e0 = __fsub_rn(sA0, pr0), e1 = __fsub_rn(sA1, pr1);
      out[(((size_t)t * 3 + 0) * BATCH + b0) * NH + n] = e0;
      out[(((size_t)t * 3 + 0) * BATCH + b1) * NH + n] = e1;
      errsq[0][0][n] = __fmul_rn(e0, e0);
      errsq[0][1][n] = __fmul_rn(e1, e1);
      float m0 = __fmul_rn(e0, 0.5f), m1 = __fmul_rn(e1, 0.5f);
      float t0 = __fadd_rn(__fmaf_rn(m0, p0a, pr0), sB0);
      float t1 = __fadd_rn(__fmaf_rn(m1, p0b, pr1), sB1);
      vX0 = __fadd_rn(__fmaf_rn(DM, vX0, t0), noi0);
      vX1 = __fadd_rn(__fmaf_rn(DM, vX1, t1), noi1);
      bool s0 = (vX0 >= 1.0f), s1 = (vX1 >= 1.0f);
      last[q][0][0][n] = s0 ? 1.f : 0.f;
      last[q][0][1][n] = s1 ? 1.f : 0.f;
      vX0 = s0 ? 0.f : vX0; vX1 = s1 ? 0.f : vX1;
    }
    __syncthreads();   // B-end: last[q][0] ready; xfer free

    // ---- D: layer 1.  h=0: inp(ff1) -> xfer; h=1: pr(p2r1)+rc(rec1) ----
    if (h == 0) {
      float i0 = 0.f, i1 = 0.f;
      dotW2r(ff1p, last[q][0][0], last[q][0][1], n, 0, 64, i0, i1);
      xfer[0][n] = i0; xfer[1][n] = i1;
    } else {
      dot2W2r(p2r1p, psp1[0], psp1[1], rec1p, last[p][1][0], last[p][1][1],
              n, 0, 64, sA0, sA1, sB0, sB1);   // sA=pr, sB=rc
    }
    __syncthreads();   // D-mid: inp available
    if (h == 1) {
      float i0 = xfer[0][n], i1 = xfer[1][n];
      float noi0 = NZ[NZI(1, b0)], noi1 = NZ[NZI(1, b1)];
      float e0 = __fsub_rn(i0, sA0), e1 = __fsub_rn(i1, sA1);
      out[(((size_t)t * 3 + 1) * BATCH + b0) * NH + n] = e0;
      out[(((size_t)t * 3 + 1) * BATCH + b1) * NH + n] = e1;
      errsq[1][0][n] = __fmul_rn(e0, e0);
      errsq[1][1][n] = __fmul_rn(e1, e1);
      float m0 = __fmul_rn(e0, 0.5f), m1 = __fmul_rn(e1, 0.5f);
      float t0 = __fadd_rn(__fmaf_rn(m0, p1a, sA0), sB0);
      float t1 = __fadd_rn(__fmaf_rn(m1, p1b, sA1), sB1);
      vX0 = __fadd_rn(__fmaf_rn(DM, vX0, t0), noi0);
      vX1 = __fadd_rn(__fmaf_rn(DM, vX1, t1), noi1);
      bool s0 = (vX0 >= 1.0f), s1 = (vX1 >= 1.0f);
      last[q][1][0][n] = s0 ? 1.f : 0.f;
      last[q][1][1][n] = s1 ? 1.f : 0.f;
      vX0 = s0 ? 0.f : vX0; vX1 = s1 ? 0.f : vX1;
    }
    __syncthreads();   // D-end: last[q][1] ready; xfer free

    // ---- E: layer 2.  h=0: inp(ff2); h=1: rc(rec2) -> xfer ----
    if (h == 0) {
      sA0 = 0.f; sA1 = 0.f;
      dotW2r(ff2p, last[q][1][0], last[q][1][1], n, 0, 64, sA0, sA1);
    } else {
      float rc0 = 0.f, rc1 = 0.f;
      dotW2r(rec2p, last[p][2][0], last[p][2][1], n, 0, 64, rc0, rc1);
      xfer[0][n] = rc0; xfer[1][n] = rc1;
    }
    __syncthreads();   // E-mid: rc available
    if (h == 0) {
      float rc0 = xfer[0][n], rc1 = xfer[1][n];
      float noi0 = NZ[NZI(2, b0)], noi1 = NZ[NZI(2, b1)];
      float e0 = sA0, e1 = sA1;
      out[(((size_t)t * 3 + 2) * BATCH + b0) * NH + n] = e0;
      out[(((size_t)t * 3 + 2) * BATCH + b1) * NH + n] = e1;
      errsq[2][0][n] = __fmul_rn(e0, e0);
      errsq[2][1][n] = __fmul_rn(e1, e1);
      float m0 = __fmul_rn(e0, 0.5f), m1 = __fmul_rn(e1, 0.5f);
      float t0 = __fadd_rn(__fmaf_rn(m0, p2a, 0.0f), rc0);
      float t1 = __fadd_rn(__fmaf_rn(m1, p2b, 0.0f), rc1);
      vY0 = __fadd_rn(__fmaf_rn(DM, vY0, t0), noi0);
      vY1 = __fadd_rn(__fmaf_rn(DM, vY1, t1), noi1);
      bool s0 = (vY0 >= 1.0f), s1 = (vY1 >= 1.0f);
      last[q][2][0][n] = s0 ? 1.f : 0.f;
      last[q][2][1][n] = s1 ? 1.f : 0.f;
      vY0 = s0 ? 0.f : vY0; vY1 = s1 ? 0.f : vY1;
    }
    __syncthreads();   // E-end: errsq complete

    // ---- F: strict sequential err^2 sums: 6 chains on 6 lanes ----
    if (tid < 6) {
      const int l = tid >> 1, rr = tid & 1;
      const float4* s4 = (const float4*)errsq[l][rr];
      float acc = 0.f;
      #pragma unroll 16
      for (int k4 = 0; k4 < 64; ++k4) {
        float4 v = s4[k4];
        acc = __fadd_rn(acc, v.x); acc = __fadd_rn(acc, v.y);
        acc = __fadd_rn(acc, v.z); acc = __fadd_rn(acc, v.w);
      }
      evsum[l][rr] = acc;
    }
    __syncthreads();   // F-end

    // ---- G: precision EMA (replicated; identical arithmetic) ----
    {
      float ev;
      ev = __fadd_rn(__fmul_rn(evsum[0][0], 0.00390625f), 1e-6f);
      p0a = __fmaf_rn(0.98f, p0a, __fmul_rn(0.02f, 1.0f / ev));
      ev = __fadd_rn(__fmul_rn(evsum[0][1], 0.00390625f), 1e-6f);
      p0b = __fmaf_rn(0.98f, p0b, __fmul_rn(0.02f, 1.0f / ev));
      ev = __fadd_rn(__fmul_rn(evsum[1][0], 0.00390625f), 1e-6f);
      p1a = __fmaf_rn(0.98f, p1a, __fmul_rn(0.02f, 1.0f / ev));
      ev = __fadd_rn(__fmul_rn(evsum[1][1], 0.00390625f), 1e-6f);
      p1b = __fmaf_rn(0.98f, p1b, __fmul_rn(0.02f, 1.0f / ev));
      ev = __fadd_rn(__fmul_rn(evsum[2][0], 0.00390625f), 1e-6f);
      p2a = __fmaf_rn(0.98f, p2a, __fmul_rn(0.02f, 1.0f / ev));
      ev = __fadd_rn(__fmul_rn(evsum[2][1], 0.00390625f), 1e-6f);
      p2b = __fmaf_rn(0.98f, p2b, __fmul_rn(0.02f, 1.0f / ev));
    }
#undef NZI
  }
}

// ======================= fallback (verified R5 kernel) =======================
__device__ __forceinline__ float dot_lds(const float* __restrict__ a,
                                         const float* __restrict__ W,
                                         int n, int K) {
  float acc = 0.f;
  #pragma unroll 8
  for (int k = 0; k < K; ++k)
    acc = __fmaf_rn(a[k], W[k * NH + n], acc);
  return acc;
}

__device__ __forceinline__ float dot_rec(const float* __restrict__ a,
                                         const float* __restrict__ W, int n) {
  float acc = 0.f;
  #pragma unroll 8
  for (int k = 0; k < NH; ++k) {
    float w = (k == n) ? 0.f : W[k * NH + n];
    acc = __fmaf_rn(a[k], w, acc);
  }
  return acc;
}

__global__ __launch_bounds__(NH)
void wm_kernel_mono(const float* __restrict__ sensory,
                    const float* __restrict__ ff0, const float* __restrict__ ff1,
                    const float* __restrict__ ff2,
                    const float* __restrict__ rec0, const float* __restrict__ rec1,
                    const float* __restrict__ rec2,
                    const float* __restrict__ pred0, const float* __restrict__ pred1,
                    const float* __restrict__ p2r0, const float* __restrict__ p2r1,
                    float* __restrict__ out) {
  const int b = blockIdx.x;
  const int n = threadIdx.x;

  __shared__ float last[2][3][NH];
  __shared__ float psp[NH];
  __shared__ float sens[NS];
  __shared__ float errsq[3][NH];
  __shared__ float evsum[3];
  __shared__ uint32_t keys[TSTEPS][5][2];

  if (n < TSTEPS) {
    uint32_t fk0, fk1;
    tf2x32(0u, 42u, 0u, (uint32_t)n, fk0, fk1);
    #pragma unroll
    for (int i = 0; i < 5; ++i) {
      uint32_t s0, s1;
      tf2x32(fk0, fk1, 0u, (uint32_t)i, s0, s1);
      keys[n][i][0] = s0; keys[n][i][1] = s1;
    }
  }
  for (int i = 0; i < 3; ++i) { last[0][i][n] = 0.f; last[1][i][n] = 0.f; }

  float v0 = 0.f, v1 = 0.f, v2 = 0.f, pv0 = 0.f, pv1 = 0.f;
  float prec0 = 1.f, prec1 = 1.f, prec2 = 1.f;
  const float DM = (float)0.951229424500714009;
  const float DP = (float)0.980198673306755250;
  const uint32_t j = (uint32_t)(b * NH + n);

  __syncthreads();

  for (int t = 0; t < TSTEPS; ++t) {
    const int p = t & 1, q = p ^ 1;

    if (n < NS) sens[n] = sensory[((size_t)t * BATCH + b) * NS + n];
    {
      float acc = dot_lds(last[p][1], pred0, n, NH);
      float pn = __fmul_rn(0.01f, jax_normal(keys[t][3][0], keys[t][3][1], j));
      pv0 = __fadd_rn(__fmaf_rn(DP, pv0, acc), pn);
      bool s = (pv0 >= 1.0f);
      psp[n] = s ? 1.f : 0.f;
      pv0 = s ? 0.f : pv0;
    }
    __syncthreads();

    {
      float pr  = dot_lds(psp, p2r0, n, NH);
      float inp = dot_lds(sens, ff0, n, NS);
      float rc  = dot_rec(last[p][0], rec0, n);
      float err = __fsub_rn(inp, pr);
      out[(((size_t)t * 3 + 0) * BATCH + b) * NH + n] = err;
      errsq[0][n] = __fmul_rn(err, err);
      float m1  = __fmul_rn(err, 0.5f);
      float tot = __fadd_rn(__fmaf_rn(m1, prec0, pr), rc);
      float noi = __fmul_rn(0.02f, jax_normal(keys[t][0][0], keys[t][0][1], j));
      v0 = __fadd_rn(__fmaf_rn(DM, v0, tot), noi);
      bool s = (v0 >= 1.0f);
      last[q][0][n] = s ? 1.f : 0.f;
      v0 = s ? 0.f : v0;
    }
    __syncthreads();

    {
      float acc = dot_lds(last[p][2], pred1, n, NH);
      float pn = __fmul_rn(0.01f, jax_normal(keys[t][4][0], keys[t][4][1], j));
      pv1 = __fadd_rn(__fmaf_rn(DP, pv1, acc), pn);
      bool s = (pv1 >= 1.0f);
      psp[n] = s ? 1.f : 0.f;
      pv1 = s ? 0.f : pv1;
    }
    __syncthreads();

    {
      float pr  = dot_lds(psp, p2r1, n, NH);
      float inp = dot_lds(last[q][0], ff1, n, NH);
      float rc  = dot_rec(last[p][1], rec1, n);
      float err = __fsub_rn(inp, pr);
      out[(((size_t)t * 3 + 1) * BATCH + b) * NH + n] = err;
      errsq[1][n] = __fmul_rn(err, err);
      float m1  = __fmul_rn(err, 0.5f);
      float tot = __fadd_rn(__fmaf_rn(m1, prec1, pr), rc);
      float noi = __fmul_rn(0.02f, jax_normal(keys[t][1][0], keys[t][1][1], j));
      v1 = __fadd_rn(__fmaf_rn(DM, v1, tot), noi);
      bool s = (v1 >= 1.0f);
      last[q][1][n] = s ? 1.f : 0.f;
      v1 = s ? 0.f : v1;
    }
    __syncthreads();

    {
      float inp = dot_lds(last[q][1], ff2, n, NH);
      float rc  = dot_rec(last[p][2], rec2, n);
      float err = inp;
      out[(((size_t)t * 3 + 2) * BATCH + b) * NH + n] = err;
      errsq[2][n] = __fmul_rn(err, err);
      float m1  = __fmul_rn(err, 0.5f);
      float tot = __fadd_rn(__fmaf_rn(m1, prec2, 0.0f), rc);
      float noi = __fmul_rn(0.02f, jax_normal(keys[t][2][0], keys[t][2][1], j));
      v2 = __fadd_rn(__fmaf_rn(DM, v2, tot), noi);
      bool s = (v2 >= 1.0f);
      last[q][2][n] = s ? 1.f : 0.f;
      v2 = s ? 0.f : v2;
    }
    __syncthreads();

    if (((n & 63) == 0) && n < 192) {
      const float* s = errsq[n >> 6];
      float acc = 0.f;
      #pragma unroll 32
      for (int k = 0; k < NH; ++k) acc = __fadd_rn(acc, s[k]);
      evsum[n >> 6] = acc;
    }
    __syncthreads();

    {
      float ev0 = __fadd_rn(__fmul_rn(evsum[0], 0.00390625f), 1e-6f);
      float ev1 = __fadd_rn(__fmul_rn(evsum[1], 0.00390625f), 1e-6f);
      float ev2 = __fadd_rn(__fmul_rn(evsum[2], 0.00390625f), 1e-6f);
      prec0 = __fmaf_rn(0.98f, prec0, __fmul_rn(0.02f, 1.0f / ev0));
      prec1 = __fmaf_rn(0.98f, prec1, __fmul_rn(0.02f, 1.0f / ev1));
      prec2 = __fmaf_rn(0.98f, prec2, __fmul_rn(0.02f, 1.0f / ev2));
    }
  }
}

extern "C" void kernel_launch(void* const* d_in, const int* in_sizes, int n_in,
                              void* d_out, int out_size, void* d_ws, size_t ws_size,
                              hipStream_t stream) {
  (void)in_sizes; (void)n_in; (void)out_size;
  const float* sensory = (const float*)d_in[0];
  const float* ff0  = (const float*)d_in[1];
  const float* ff1  = (const float*)d_in[2];
  const float* ff2  = (const float*)d_in[3];
  const float* rec0 = (const float*)d_in[4];
  const float* rec1 = (const float*)d_in[5];
  const float* rec2 = (const float*)d_in[6];
  const float* pred0 = (const float*)d_in[7];
  const float* pred1 = (const float*)d_in[8];
  const float* p2r0 = (const float*)d_in[9];
  const float* p2r1 = (const float*)d_in[10];
  float* out = (float*)d_out;

  // ws layout (floats): packed weights then noise.
  const size_t OFF_PRED0 = 0, OFF_PRED1 = 65536, OFF_P2R0 = 131072,
               OFF_REC0 = 196608, OFF_FF0 = 262144, OFF_P2R1 = 294912,
               OFF_FF1 = 360448, OFF_REC1 = 425984, OFF_FF2 = 491520,
               OFF_REC2 = 557056, OFF_NZ = 655360;
  const size_t NZ_FLOATS = (size_t)TSTEPS * 5 * BATCH * NH;  // 65,536,000
  const size_t NEED = (OFF_NZ + NZ_FLOATS) * sizeof(float);

  if (ws_size >= NEED) {
    float* W = (float*)d_ws;
    pack_w<<<dim3(NH * NH / 256), dim3(256), 0, stream>>>(pred0, W + OFF_PRED0, NH, 0);
    pack_w<<<dim3(NH * NH / 256), dim3(256), 0, stream>>>(pred1, W + OFF_PRED1, NH, 0);
    pack_w<<<dim3(NH * NH / 256), dim3(256), 0, stream>>>(p2r0,  W + OFF_P2R0,  NH, 0);
    pack_w<<<dim3(NH * NH / 256), dim3(256), 0, stream>>>(rec0,  W + OFF_REC0,  NH, 1);
    pack_w<<<dim3(NS * NH / 256), dim3(256), 0, stream>>>(ff0,   W + OFF_FF0,   NS, 0);
    pack_w<<<dim3(NH * NH / 256), dim3(256), 0, stream>>>(p2r1,  W + OFF_P2R1,  NH, 0);
    pack_w<<<dim3(NH * NH / 256), dim3(256), 0, stream>>>(ff1,   W + OFF_FF1,   NH, 0);
    pack_w<<<dim3(NH * NH / 256), dim3(256), 0, stream>>>(rec1,  W + OFF_REC1,  NH, 1);
    pack_w<<<dim3(NH * NH / 256), dim3(256), 0, stream>>>(ff2,   W + OFF_FF2,   NH, 0);
    pack_w<<<dim3(NH * NH / 256), dim3(256), 0, stream>>>(rec2,  W + OFF_REC2,  NH, 1);
    gen_noise<<<dim3((unsigned)(NZ_FLOATS / 256)), dim3(256), 0, stream>>>(W + OFF_NZ);
    wm_fast7<<<dim3(BATCH / 2), dim3(512), 0, stream>>>(
        sensory,
        (const float4*)(W + OFF_PRED0), (const float4*)(W + OFF_PRED1),
        (const float4*)(W + OFF_P2R0),  (const float4*)(W + OFF_REC0),
        (const float4*)(W + OFF_FF0),   (const float4*)(W + OFF_P2R1),
        (const float4*)(W + OFF_FF1),   (const float4*)(W + OFF_REC1),
        (const float4*)(W + OFF_FF2),   (const float4*)(W + OFF_REC2),
        W + OFF_NZ, out);
  } else {
    wm_kernel_mono<<<dim3(BATCH), dim3(NH), 0, stream>>>(
        sensory, ff0, ff1, ff2, rec0, rec1, rec2,
        pred0, pred1, p2r0, p2r1, out);
  }
}

// Round 15
// 4322.059 us; speedup vs baseline: 1.1843x; 1.0471x over previous
//
#include <hip/hip_runtime.h>
#include <stdint.h>

#define TSTEPS 100
#define BATCH  512
#define NH     256
#define NS     128

__device__ __forceinline__ uint32_t rotl32(uint32_t x, int r) {
  return (x << r) | (x >> (32 - r));
}

// Threefry-2x32-20, exactly as jax/_src/prng.py
__device__ __forceinline__ void tf2x32(uint32_t k0, uint32_t k1,
                                       uint32_t c0, uint32_t c1,
                                       uint32_t& o0, uint32_t& o1) {
  const uint32_t ks2 = k0 ^ k1 ^ 0x1BD11BDAu;
  uint32_t x0 = c0 + k0, x1 = c1 + k1;
#define TFR(r) { x0 += x1; x1 = rotl32(x1, r); x1 ^= x0; }
  TFR(13) TFR(15) TFR(26) TFR(6)
  x0 += k1;  x1 += ks2 + 1u;
  TFR(17) TFR(29) TFR(16) TFR(24)
  x0 += ks2; x1 += k0 + 2u;
  TFR(13) TFR(15) TFR(26) TFR(6)
  x0 += k0;  x1 += k1 + 3u;
  TFR(17) TFR(29) TFR(16) TFR(24)
  x0 += k1;  x1 += ks2 + 4u;
  TFR(13) TFR(15) TFR(26) TFR(6)
  x0 += ks2; x1 += k0 + 5u;
#undef TFR
  o0 = x0; o1 = x1;
}

// XLA:CPU GenerateVF32Log (Cephes port, FMA form). Inputs in (0,1], normal.
__device__ __forceinline__ float xla_vf32_log(float a) {
  uint32_t bits = __float_as_uint(a);
  float e = __fadd_rn((float)((int)(bits >> 23) - 127), 1.0f);
  float x = __uint_as_float((bits & 0x007FFFFFu) | 0x3F000000u);
  const bool mask = x < 0.707106781186547524f;
  float tmp = mask ? x : 0.0f;
  x = __fsub_rn(x, 1.0f);
  e = mask ? __fsub_rn(e, 1.0f) : e;
  x = __fadd_rn(x, tmp);
  float z = __fmul_rn(x, x);
  float y = 7.0376836292e-2f;
  y = __fmaf_rn(y, x, -1.1514610310e-1f);
  y = __fmaf_rn(y, x, 1.1676998740e-1f);
  y = __fmaf_rn(y, x, -1.2420140846e-1f);
  y = __fmaf_rn(y, x, 1.4249322787e-1f);
  y = __fmaf_rn(y, x, -1.6668057665e-1f);
  y = __fmaf_rn(y, x, 2.0000714765e-1f);
  y = __fmaf_rn(y, x, -2.4999993993e-1f);
  y = __fmaf_rn(y, x, 3.3333331174e-1f);
  y = __fmul_rn(y, x);
  y = __fmul_rn(y, z);
  y = __fmaf_rn(e, -2.12194440e-4f, y);
  y = __fmaf_rn(-0.5f, z, y);
  x = __fadd_rn(x, y);
  x = __fmaf_rn(e, 0.693359375f, x);
  return x;
}

// sqrt(2)*erfinv(u): chlo erf_inv f32 (Giles) + EmitLog1p, FMA-contracted.
__device__ __forceinline__ float xla_sqrt2_erfinv(float u) {
  float nxx = -__fmul_rn(u, u);
  float w;
  if (fabsf(nxx) < 1e-4f) {
    w = -__fmul_rn(__fmaf_rn(-0.5f, nxx, 1.0f), nxx);
  } else {
    w = -xla_vf32_log(__fadd_rn(nxx, 1.0f));
  }
  float p;
  if (w < 5.0f) {
    float t = __fsub_rn(w, 2.5f);
    p = 2.81022636e-08f;
    p = __fmaf_rn(p, t, 3.43273939e-07f);
    p = __fmaf_rn(p, t, -3.5233877e-06f);
    p = __fmaf_rn(p, t, -4.39150654e-06f);
    p = __fmaf_rn(p, t, 0.00021858087f);
    p = __fmaf_rn(p, t, -0.00125372503f);
    p = __fmaf_rn(p, t, -0.00417768164f);
    p = __fmaf_rn(p, t, 0.246640727f);
    p = __fmaf_rn(p, t, 1.50140941f);
  } else {
    float t = __fsub_rn(__fsqrt_rn(w), 3.0f);
    p = -0.000200214257f;
    p = __fmaf_rn(p, t, 0.000100950558f);
    p = __fmaf_rn(p, t, 0.00134934322f);
    p = __fmaf_rn(p, t, -0.00367342844f);
    p = __fmaf_rn(p, t, 0.00573950773f);
    p = __fmaf_rn(p, t, -0.0076224613f);
    p = __fmaf_rn(p, t, 0.00943887047f);
    p = __fmaf_rn(p, t, 1.00167406f);
    p = __fmaf_rn(p, t, 2.83297682f);
  }
  return __fmul_rn((float)1.4142135623730951, __fmul_rn(p, u));
}

// jax.random.normal element j under key (k0,k1), threefry-partitionable.
__device__ __forceinline__ float jax_normal(uint32_t k0, uint32_t k1, uint32_t j) {
  uint32_t o0, o1;
  tf2x32(k0, k1, 0u, j, o0, o1);
  const uint32_t bits = o0 ^ o1;
  float f = __fsub_rn(__uint_as_float((bits >> 9) | 0x3f800000u), 1.0f);
  const float LO = -0.99999994f;
  float u = __fmaf_rn(f, 2.0f, LO);
  u = fmaxf(LO, u);
  return xla_sqrt2_erfinv(u);
}

// Pack W[K][256] -> P[k/4][n][4]; optionally zero diagonal (rec masks).
__global__ void pack_w(const float* __restrict__ src, float* __restrict__ dst,
                       int K, int zero_diag) {
  int tid = blockIdx.x * 256 + threadIdx.x;
  if (tid >= K * NH) return;
  int k = tid >> 8, n = tid & 255;
  float v = src[tid];
  if (zero_diag && k == n) v = 0.f;
  dst[(((k >> 2) * NH) + n) * 4 + (k & 3)] = v;
}

// Precompute all scaled noise draws: NZ[((t*5+d)*BATCH+b)*NH+n].
__global__ __launch_bounds__(256)
void gen_noise(float* __restrict__ NZ) {
  uint32_t idx = blockIdx.x * 256u + threadIdx.x;
  uint32_t j = idx & 131071u;          // b*NH + n
  uint32_t td = idx >> 17;             // t*5 + d  (< 500)
  uint32_t t = td / 5u, d = td - 5u * t;
  uint32_t fk0, fk1, k0, k1;
  tf2x32(0u, 42u, 0u, t, fk0, fk1);
  tf2x32(fk0, fk1, 0u, d, k0, k1);
  float z = jax_normal(k0, k1, j);
  float scale = (d >= 3u) ? 0.01f : 0.02f;
  NZ[idx] = __fmul_rn(scale, z);
}

// ===== mask utilities =====
// Read a 256-bit spike mask (4xu64 in LDS, wave-uniform) into scalar regs.
__device__ __forceinline__ void read_mask(const uint64_t* __restrict__ s,
                                          uint64_t m[4]) {
  #pragma unroll
  for (int i = 0; i < 4; ++i) {
    uint2 v = *reinterpret_cast<const uint2*>(s + i);
    uint32_t lo = (uint32_t)__builtin_amdgcn_readfirstlane((int)v.x);
    uint32_t hi = (uint32_t)__builtin_amdgcn_readfirstlane((int)v.y);
    m[i] = (((uint64_t)hi) << 32) | (uint64_t)lo;
  }
}

#define XB(bits, bit) (((bits) & (bit)) ? 1.0f : 0.0f)

// ===== mask dots: x rebuilt from bitmask in {0.0f,1.0f}; the executed
// fma(x, w, acc) chain is operand-identical to the float-x version (same
// spikes, same k-ascending order) -> bit-exact. One weight load feeds 2 rows.
__device__ __forceinline__ void dotM2r(const float4* __restrict__ P,
                                       const uint64_t M0[4], const uint64_t M1[4],
                                       int n, float& r0, float& r1) {
  float a0 = r0, a1 = r1;
  #pragma unroll
  for (int i = 0; i < 4; ++i) {
    const uint64_t m0 = M0[i], m1 = M1[i];
    #pragma unroll 4
    for (int kk = 0; kk < 16; ++kk) {
      const int k4 = i * 16 + kk;
      float4 w = P[k4 * NH + n];
      uint32_t b0 = (uint32_t)(m0 >> (kk * 4)) & 0xFu;
      uint32_t b1 = (uint32_t)(m1 >> (kk * 4)) & 0xFu;
      a0 = __fmaf_rn(XB(b0, 1u), w.x, a0); a1 = __fmaf_rn(XB(b1, 1u), w.x, a1);
      a0 = __fmaf_rn(XB(b0, 2u), w.y, a0); a1 = __fmaf_rn(XB(b1, 2u), w.y, a1);
      a0 = __fmaf_rn(XB(b0, 4u), w.z, a0); a1 = __fmaf_rn(XB(b1, 4u), w.z, a1);
      a0 = __fmaf_rn(XB(b0, 8u), w.w, a0); a1 = __fmaf_rn(XB(b1, 8u), w.w, a1);
    }
  }
  r0 = a0; r1 = a1;
}

// two mask-matrices interleaved (2 rows each)
__device__ __forceinline__ void dot2M2r(const float4* __restrict__ PA,
                                        const uint64_t A0[4], const uint64_t A1[4],
                                        const float4* __restrict__ PB,
                                        const uint64_t B0[4], const uint64_t B1[4],
                                        int n,
                                        float& rA0, float& rA1,
                                        float& rB0, float& rB1) {
  float a0 = rA0, a1 = rA1, b0 = rB0, b1 = rB1;
  #pragma unroll
  for (int i = 0; i < 4; ++i) {
    const uint64_t ma0 = A0[i], ma1 = A1[i], mb0 = B0[i], mb1 = B1[i];
    #pragma unroll 2
    for (int kk = 0; kk < 16; ++kk) {
      const int k4 = i * 16 + kk;
      float4 wa = PA[k4 * NH + n];
      float4 wb = PB[k4 * NH + n];
      uint32_t qa0 = (uint32_t)(ma0 >> (kk * 4)) & 0xFu;
      uint32_t qa1 = (uint32_t)(ma1 >> (kk * 4)) & 0xFu;
      uint32_t qb0 = (uint32_t)(mb0 >> (kk * 4)) & 0xFu;
      uint32_t qb1 = (uint32_t)(mb1 >> (kk * 4)) & 0xFu;
      a0 = __fmaf_rn(XB(qa0, 1u), wa.x, a0); a1 = __fmaf_rn(XB(qa1, 1u), wa.x, a1);
      b0 = __fmaf_rn(XB(qb0, 1u), wb.x, b0); b1 = __fmaf_rn(XB(qb1, 1u), wb.x, b1);
      a0 = __fmaf_rn(XB(qa0, 2u), wa.y, a0); a1 = __fmaf_rn(XB(qa1, 2u), wa.y, a1);
      b0 = __fmaf_rn(XB(qb0, 2u), wb.y, b0); b1 = __fmaf_rn(XB(qb1, 2u), wb.y, b1);
      a0 = __fmaf_rn(XB(qa0, 4u), wa.z, a0); a1 = __fmaf_rn(XB(qa1, 4u), wa.z, a1);
      b0 = __fmaf_rn(XB(qb0, 4u), wb.z, b0); b1 = __fmaf_rn(XB(qb1, 4u), wb.z, b1);
      a0 = __fmaf_rn(XB(qa0, 8u), wa.w, a0); a1 = __fmaf_rn(XB(qa1, 8u), wa.w, a1);
      b0 = __fmaf_rn(XB(qb0, 8u), wb.w, b0); b1 = __fmaf_rn(XB(qb1, 8u), wb.w, b1);
    }
  }
  rA0 = a0; rA1 = a1; rB0 = b0; rB1 = b1;
}

// ff0 (float sens x) + rec0 (mask x), k4 0..31; then rec0-only 32..63.
__device__ __forceinline__ void dotFM2r(const float4* __restrict__ Pf,
                                        const float* __restrict__ Xs0,
                                        const float* __restrict__ Xs1,
                                        const float4* __restrict__ Pm,
                                        const uint64_t M0[4], const uint64_t M1[4],
                                        int n,
                                        float& rf0, float& rf1,
                                        float& rm0, float& rm1) {
  float f0 = rf0, f1 = rf1, g0 = rm0, g1 = rm1;
  #pragma unroll
  for (int i = 0; i < 2; ++i) {
    const uint64_t m0 = M0[i], m1 = M1[i];
    #pragma unroll 2
    for (int kk = 0; kk < 16; ++kk) {
      const int k4 = i * 16 + kk;
      float4 wf = Pf[k4 * NH + n];
      float4 wm = Pm[k4 * NH + n];
      float4 x0 = *reinterpret_cast<const float4*>(Xs0 + 4 * k4);
      float4 x1 = *reinterpret_cast<const float4*>(Xs1 + 4 * k4);
      uint32_t b0 = (uint32_t)(m0 >> (kk * 4)) & 0xFu;
      uint32_t b1 = (uint32_t)(m1 >> (kk * 4)) & 0xFu;
      f0 = __fmaf_rn(x0.x, wf.x, f0); f1 = __fmaf_rn(x1.x, wf.x, f1);
      g0 = __fmaf_rn(XB(b0, 1u), wm.x, g0); g1 = __fmaf_rn(XB(b1, 1u), wm.x, g1);
      f0 = __fmaf_rn(x0.y, wf.y, f0); f1 = __fmaf_rn(x1.y, wf.y, f1);
      g0 = __fmaf_rn(XB(b0, 2u), wm.y, g0); g1 = __fmaf_rn(XB(b1, 2u), wm.y, g1);
      f0 = __fmaf_rn(x0.z, wf.z, f0); f1 = __fmaf_rn(x1.z, wf.z, f1);
      g0 = __fmaf_rn(XB(b0, 4u), wm.z, g0); g1 = __fmaf_rn(XB(b1, 4u), wm.z, g1);
      f0 = __fmaf_rn(x0.w, wf.w, f0); f1 = __fmaf_rn(x1.w, wf.w, f1);
      g0 = __fmaf_rn(XB(b0, 8u), wm.w, g0); g1 = __fmaf_rn(XB(b1, 8u), wm.w, g1);
    }
  }
  #pragma unroll
  for (int i = 2; i < 4; ++i) {
    const uint64_t m0 = M0[i], m1 = M1[i];
    #pragma unroll 4
    for (int kk = 0; kk < 16; ++kk) {
      const int k4 = i * 16 + kk;
      float4 wm = Pm[k4 * NH + n];
      uint32_t b0 = (uint32_t)(m0 >> (kk * 4)) & 0xFu;
      uint32_t b1 = (uint32_t)(m1 >> (kk * 4)) & 0xFu;
      g0 = __fmaf_rn(XB(b0, 1u), wm.x, g0); g1 = __fmaf_rn(XB(b1, 1u), wm.x, g1);
      g0 = __fmaf_rn(XB(b0, 2u), wm.y, g0); g1 = __fmaf_rn(XB(b1, 2u), wm.y, g1);
      g0 = __fmaf_rn(XB(b0, 4u), wm.z, g0); g1 = __fmaf_rn(XB(b1, 4u), wm.z, g1);
      g0 = __fmaf_rn(XB(b0, 8u), wm.w, g0); g1 = __fmaf_rn(XB(b1, 8u), wm.w, g1);
    }
  }
  rf0 = f0; rf1 = f1; rm0 = g0; rm1 = g1;
}

// ===== main: R14 structure + spike-bitmask x (zero LDS reads in dots) =====
__global__ __launch_bounds__(512)
void wm_fast8(const float* __restrict__ sensory,
              const float4* __restrict__ pred0p, const float4* __restrict__ pred1p,
              const float4* __restrict__ p2r0p,  const float4* __restrict__ rec0p,
              const float4* __restrict__ ff0p,   const float4* __restrict__ p2r1p,
              const float4* __restrict__ ff1p,   const float4* __restrict__ rec1p,
              const float4* __restrict__ ff2p,   const float4* __restrict__ rec2p,
              const float* __restrict__ NZ,
              float* __restrict__ out) {
  const int tid = threadIdx.x;
  const int n = tid & 255;         // neuron
  const int h = tid >> 8;          // chain-subset selector (wave-uniform)
  const int lane = tid & 63;
  const int wv = (tid & 255) >> 6; // wave index within h-group (0..3)
  const int b0 = blockIdx.x * 2, b1 = b0 + 1;

  __shared__ uint64_t lmask[2][3][2][4];  // [pp][layer][row][wv]
  __shared__ uint64_t pmask0[2][4];       // psp0 [row][wv]
  __shared__ uint64_t pmask1[2][4];
  __shared__ __align__(16) float sens[2][NS];
  __shared__ __align__(16) float errsq[3][2][NH];
  __shared__ __align__(16) float xfer[2][NH];
  __shared__ float evsum[3][2];

  if (tid < 48) ((uint64_t*)lmask)[tid] = 0ull;

  // h=0 owns: pred0-v, layer0-v, layer2-v (x2 rows). h=1: pred1-v, layer1-v.
  float pvR0 = 0.f, pvR1 = 0.f;
  float vX0 = 0.f, vX1 = 0.f;      // layer0 (h=0) / layer1 (h=1)
  float vY0 = 0.f, vY1 = 0.f;      // layer2 (h=0 only)
  float p0a = 1.f, p0b = 1.f, p1a = 1.f, p1b = 1.f, p2a = 1.f, p2b = 1.f;
  const float DM = (float)0.951229424500714009;  // f32(exp(-1/20))
  const float DP = (float)0.980198673306755250;  // f32(exp(-1/50))

  __syncthreads();

  for (int t = 0; t < TSTEPS; ++t) {
    const int p = t & 1, q = p ^ 1;
    const size_t t5 = (size_t)t * 5 * BATCH * NH;
#define NZI(d, bb) (t5 + ((size_t)(d) * BATCH + (bb)) * NH + n)

    // ---- A: pred-LIF 0 (h=0) / pred-LIF 1 (h=1), both rows ----
    if (tid < 2 * NS) {
      int rr = tid >> 7, kk = tid & 127;
      sens[rr][kk] = sensory[((size_t)t * BATCH + b0 + rr) * NS + kk];
    }
    if (h == 0) {
      uint64_t M0[4], M1[4];
      read_mask(lmask[p][1][0], M0);
      read_mask(lmask[p][1][1], M1);
      float a0 = 0.f, a1 = 0.f;
      dotM2r(pred0p, M0, M1, n, a0, a1);
      float pn0 = NZ[NZI(3, b0)], pn1 = NZ[NZI(3, b1)];
      pvR0 = __fadd_rn(__fmaf_rn(DP, pvR0, a0), pn0);
      bool s0 = (pvR0 >= 1.0f);
      pvR0 = s0 ? 0.f : pvR0;
      pvR1 = __fadd_rn(__fmaf_rn(DP, pvR1, a1), pn1);
      bool s1 = (pvR1 >= 1.0f);
      pvR1 = s1 ? 0.f : pvR1;
      uint64_t bm0 = __ballot(s0), bm1 = __ballot(s1);
      if (lane == 0) { pmask0[0][wv] = bm0; pmask0[1][wv] = bm1; }
    } else {
      uint64_t M0[4], M1[4];
      read_mask(lmask[p][2][0], M0);
      read_mask(lmask[p][2][1], M1);
      float a0 = 0.f, a1 = 0.f;
      dotM2r(pred1p, M0, M1, n, a0, a1);
      float pn0 = NZ[NZI(4, b0)], pn1 = NZ[NZI(4, b1)];
      pvR0 = __fadd_rn(__fmaf_rn(DP, pvR0, a0), pn0);
      bool s0 = (pvR0 >= 1.0f);
      pvR0 = s0 ? 0.f : pvR0;
      pvR1 = __fadd_rn(__fmaf_rn(DP, pvR1, a1), pn1);
      bool s1 = (pvR1 >= 1.0f);
      pvR1 = s1 ? 0.f : pvR1;
      uint64_t bm0 = __ballot(s0), bm1 = __ballot(s1);
      if (lane == 0) { pmask1[0][wv] = bm0; pmask1[1][wv] = bm1; }
    }
    __syncthreads();   // A-end: pmask0, pmask1, sens ready

    // ---- B: layer 0.  h=0: inp(ff0)+rc(rec0); h=1: pr(p2r0) -> xfer ----
    float sA0 = 0.f, sA1 = 0.f, sB0 = 0.f, sB1 = 0.f;
    if (h == 0) {
      uint64_t M0[4], M1[4];
      read_mask(lmask[p][0][0], M0);
      read_mask(lmask[p][0][1], M1);
      dotFM2r(ff0p, sens[0], sens[1], rec0p, M0, M1, n, sA0, sA1, sB0, sB1);
    } else {
      uint64_t M0[4], M1[4];
      read_mask(pmask0[0], M0);
      read_mask(pmask0[1], M1);
      float pr0 = 0.f, pr1 = 0.f;
      dotM2r(p2r0p, M0, M1, n, pr0, pr1);
      xfer[0][n] = pr0; xfer[1][n] = pr1;
    }
    __syncthreads();   // B-mid: pr available
    if (h == 0) {
      float pr0 = xfer[0][n], pr1 = xfer[1][n];
      float noi0 = NZ[NZI(0, b0)], noi1 = NZ[NZI(0, b1)];
      float e0 = __fsub_rn(sA0, pr0), e1 = __fsub_rn(sA1, pr1);
      out[(((size_t)t * 3 + 0) * BATCH + b0) * NH + n] = e0;
      out[(((size_t)t * 3 + 0) * BATCH + b1) * NH + n] = e1;
      errsq[0][0][n] = __fmul_rn(e0, e0);
      errsq[0][1][n] = __fmul_rn(e1, e1);
      float m0 = __fmul_rn(e0, 0.5f), m1 = __fmul_rn(e1, 0.5f);
      float t0 = __fadd_rn(__fmaf_rn(m0, p0a, pr0), sB0);
      float t1 = __fadd_rn(__fmaf_rn(m1, p0b, pr1), sB1);
      vX0 = __fadd_rn(__fmaf_rn(DM, vX0, t0), noi0);
      vX1 = __fadd_rn(__fmaf_rn(DM, vX1, t1), noi1);
      bool s0 = (vX0 >= 1.0f), s1 = (vX1 >= 1.0f);
      vX0 = s0 ? 0.f : vX0; vX1 = s1 ? 0.f : vX1;
      uint64_t bm0 = __ballot(s0), bm1 = __ballot(s1);
      if (lane == 0) { lmask[q][0][0][wv] = bm0; lmask[q][0][1][wv] = bm1; }
    }
    __syncthreads();   // B-end: lmask[q][0] ready; xfer free

    // ---- D: layer 1.  h=0: inp(ff1) -> xfer; h=1: pr(p2r1)+rc(rec1) ----
    if (h == 0) {
      uint64_t M0[4], M1[4];
      read_mask(lmask[q][0][0], M0);
      read_mask(lmask[q][0][1], M1);
      float i0 = 0.f, i1 = 0.f;
      dotM2r(ff1p, M0, M1, n, i0, i1);
      xfer[0][n] = i0; xfer[1][n] = i1;
    } else {
      uint64_t A0[4], A1[4], B0[4], B1[4];
      read_mask(pmask1[0], A0);
      read_mask(pmask1[1], A1);
      read_mask(lmask[p][1][0], B0);
      read_mask(lmask[p][1][1], B1);
      dot2M2r(p2r1p, A0, A1, rec1p, B0, B1, n, sA0, sA1, sB0, sB1);
    }
    __syncthreads();   // D-mid: inp available
    if (h == 1) {
      float i0 = xfer[0][n], i1 = xfer[1][n];
      float noi0 = NZ[NZI(1, b0)], noi1 = NZ[NZI(1, b1)];
      float e0 = __fsub_rn(i0, sA0), e1 = __fsub_rn(i1, sA1);
      out[(((size_t)t * 3 + 1) * BATCH + b0) * NH + n] = e0;
      out[(((size_t)t * 3 + 1) * BATCH + b1) * NH + n] = e1;
      errsq[1][0][n] = __fmul_rn(e0, e0);
      errsq[1][1][n] = __fmul_rn(e1, e1);
      float m0 = __fmul_rn(e0, 0.5f), m1 = __fmul_rn(e1, 0.5f);
      float t0 = __fadd_rn(__fmaf_rn(m0, p1a, sA0), sB0);
      float t1 = __fadd_rn(__fmaf_rn(m1, p1b, sA1), sB1);
      vX0 = __fadd_rn(__fmaf_rn(DM, vX0, t0), noi0);
      vX1 = __fadd_rn(__fmaf_rn(DM, vX1, t1), noi1);
      bool s0 = (vX0 >= 1.0f), s1 = (vX1 >= 1.0f);
      vX0 = s0 ? 0.f : vX0; vX1 = s1 ? 0.f : vX1;
      uint64_t bm0 = __ballot(s0), bm1 = __ballot(s1);
      if (lane == 0) { lmask[q][1][0][wv] = bm0; lmask[q][1][1][wv] = bm1; }
    }
    __syncthreads();   // D-end: lmask[q][1] ready; xfer free

    // ---- E: layer 2.  h=0: inp(ff2); h=1: rc(rec2) -> xfer ----
    if (h == 0) {
      uint64_t M0[4], M1[4];
      read_mask(lmask[q][1][0], M0);
      read_mask(lmask[q][1][1], M1);
      sA0 = 0.f; sA1 = 0.f;
      dotM2r(ff2p, M0, M1, n, sA0, sA1);
    } else {
      uint64_t M0[4], M1[4];
      read_mask(lmask[p][2][0], M0);
      read_mask(lmask[p][2][1], M1);
      float rc0 = 0.f, rc1 = 0.f;
      dotM2r(rec2p, M0, M1, n, rc0, rc1);
      xfer[0][n] = rc0; xfer[1][n] = rc1;
    }
    __syncthreads();   // E-mid: rc available
    if (h == 0) {
      float rc0 = xfer[0][n], rc1 = xfer[1][n];
      float noi0 = NZ[NZI(2, b0)], noi1 = NZ[NZI(2, b1)];
      float e0 = sA0, e1 = sA1;
      out[(((size_t)t * 3 + 2) * BATCH + b0) * NH + n] = e0;
      out[(((size_t)t * 3 + 2) * BATCH + b1) * NH + n] = e1;
      errsq[2][0][n] = __fmul_rn(e0, e0);
      errsq[2][1][n] = __fmul_rn(e1, e1);
      float m0 = __fmul_rn(e0, 0.5f), m1 = __fmul_rn(e1, 0.5f);
      float t0 = __fadd_rn(__fmaf_rn(m0, p2a, 0.0f), rc0);
      float t1 = __fadd_rn(__fmaf_rn(m1, p2b, 0.0f), rc1);
      vY0 = __fadd_rn(__fmaf_rn(DM, vY0, t0), noi0);
      vY1 = __fadd_rn(__fmaf_rn(DM, vY1, t1), noi1);
      bool s0 = (vY0 >= 1.0f), s1 = (vY1 >= 1.0f);
      vY0 = s0 ? 0.f : vY0; vY1 = s1 ? 0.f : vY1;
      uint64_t bm0 = __ballot(s0), bm1 = __ballot(s1);
      if (lane == 0) { lmask[q][2][0][wv] = bm0; lmask[q][2][1][wv] = bm1; }
    }
    __syncthreads();   // E-end: errsq complete

    // ---- F: strict sequential err^2 sums: 6 chains on 6 lanes ----
    if (tid < 6) {
      const int l = tid >> 1, rr = tid & 1;
      const float4* s4 = (const float4*)errsq[l][rr];
      float acc = 0.f;
      #pragma unroll 16
      for (int k4 = 0; k4 < 64; ++k4) {
        float4 v = s4[k4];
        acc = __fadd_rn(acc, v.x); acc = __fadd_rn(acc, v.y);
        acc = __fadd_rn(acc, v.z); acc = __fadd_rn(acc, v.w);
      }
      evsum[l][rr] = acc;
    }
    __syncthreads();   // F-end

    // ---- G: precision EMA (replicated; identical arithmetic) ----
    {
      float ev;
      ev = __fadd_rn(__fmul_rn(evsum[0][0], 0.00390625f), 1e-6f);
      p0a = __fmaf_rn(0.98f, p0a, __fmul_rn(0.02f, 1.0f / ev));
      ev = __fadd_rn(__fmul_rn(evsum[0][1], 0.00390625f), 1e-6f);
      p0b = __fmaf_rn(0.98f, p0b, __fmul_rn(0.02f, 1.0f / ev));
      ev = __fadd_rn(__fmul_rn(evsum[1][0], 0.00390625f), 1e-6f);
      p1a = __fmaf_rn(0.98f, p1a, __fmul_rn(0.02f, 1.0f / ev));
      ev = __fadd_rn(__fmul_rn(evsum[1][1], 0.00390625f), 1e-6f);
      p1b = __fmaf_rn(0.98f, p1b, __fmul_rn(0.02f, 1.0f / ev));
      ev = __fadd_rn(__fmul_rn(evsum[2][0], 0.00390625f), 1e-6f);
      p2a = __fmaf_rn(0.98f, p2a, __fmul_rn(0.02f, 1.0f / ev));
      ev = __fadd_rn(__fmul_rn(evsum[2][1], 0.00390625f), 1e-6f);
      p2b = __fmaf_rn(0.98f, p2b, __fmul_rn(0.02f, 1.0f / ev));
    }
#undef NZI
  }
}

// ======================= fallback (verified R5 kernel) =======================
__device__ __forceinline__ float dot_lds(const float* __restrict__ a,
                                         const float* __restrict__ W,
                                         int n, int K) {
  float acc = 0.f;
  #pragma unroll 8
  for (int k = 0; k < K; ++k)
    acc = __fmaf_rn(a[k], W[k * NH + n], acc);
  return acc;
}

__device__ __forceinline__ float dot_rec(const float* __restrict__ a,
                                         const float* __restrict__ W, int n) {
  float acc = 0.f;
  #pragma unroll 8
  for (int k = 0; k < NH; ++k) {
    float w = (k == n) ? 0.f : W[k * NH + n];
    acc = __fmaf_rn(a[k], w, acc);
  }
  return acc;
}

__global__ __launch_bounds__(NH)
void wm_kernel_mono(const float* __restrict__ sensory,
                    const float* __restrict__ ff0, const float* __restrict__ ff1,
                    const float* __restrict__ ff2,
                    const float* __restrict__ rec0, const float* __restrict__ rec1,
                    const float* __restrict__ rec2,
                    const float* __restrict__ pred0, const float* __restrict__ pred1,
                    const float* __restrict__ p2r0, const float* __restrict__ p2r1,
                    float* __restrict__ out) {
  const int b = blockIdx.x;
  const int n = threadIdx.x;

  __shared__ float last[2][3][NH];
  __shared__ float psp[NH];
  __shared__ float sens[NS];
  __shared__ float errsq[3][NH];
  __shared__ float evsum[3];
  __shared__ uint32_t keys[TSTEPS][5][2];

  if (n < TSTEPS) {
    uint32_t fk0, fk1;
    tf2x32(0u, 42u, 0u, (uint32_t)n, fk0, fk1);
    #pragma unroll
    for (int i = 0; i < 5; ++i) {
      uint32_t s0, s1;
      tf2x32(fk0, fk1, 0u, (uint32_t)i, s0, s1);
      keys[n][i][0] = s0; keys[n][i][1] = s1;
    }
  }
  for (int i = 0; i < 3; ++i) { last[0][i][n] = 0.f; last[1][i][n] = 0.f; }

  float v0 = 0.f, v1 = 0.f, v2 = 0.f, pv0 = 0.f, pv1 = 0.f;
  float prec0 = 1.f, prec1 = 1.f, prec2 = 1.f;
  const float DM = (float)0.951229424500714009;
  const float DP = (float)0.980198673306755250;
  const uint32_t j = (uint32_t)(b * NH + n);

  __syncthreads();

  for (int t = 0; t < TSTEPS; ++t) {
    const int p = t & 1, q = p ^ 1;

    if (n < NS) sens[n] = sensory[((size_t)t * BATCH + b) * NS + n];
    {
      float acc = dot_lds(last[p][1], pred0, n, NH);
      float pn = __fmul_rn(0.01f, jax_normal(keys[t][3][0], keys[t][3][1], j));
      pv0 = __fadd_rn(__fmaf_rn(DP, pv0, acc), pn);
      bool s = (pv0 >= 1.0f);
      psp[n] = s ? 1.f : 0.f;
      pv0 = s ? 0.f : pv0;
    }
    __syncthreads();

    {
      float pr  = dot_lds(psp, p2r0, n, NH);
      float inp = dot_lds(sens, ff0, n, NS);
      float rc  = dot_rec(last[p][0], rec0, n);
      float err = __fsub_rn(inp, pr);
      out[(((size_t)t * 3 + 0) * BATCH + b) * NH + n] = err;
      errsq[0][n] = __fmul_rn(err, err);
      float m1  = __fmul_rn(err, 0.5f);
      float tot = __fadd_rn(__fmaf_rn(m1, prec0, pr), rc);
      float noi = __fmul_rn(0.02f, jax_normal(keys[t][0][0], keys[t][0][1], j));
      v0 = __fadd_rn(__fmaf_rn(DM, v0, tot), noi);
      bool s = (v0 >= 1.0f);
      last[q][0][n] = s ? 1.f : 0.f;
      v0 = s ? 0.f : v0;
    }
    __syncthreads();

    {
      float acc = dot_lds(last[p][2], pred1, n, NH);
      float pn = __fmul_rn(0.01f, jax_normal(keys[t][4][0], keys[t][4][1], j));
      pv1 = __fadd_rn(__fmaf_rn(DP, pv1, acc), pn);
      bool s = (pv1 >= 1.0f);
      psp[n] = s ? 1.f : 0.f;
      pv1 = s ? 0.f : pv1;
    }
    __syncthreads();

    {
      float pr  = dot_lds(psp, p2r1, n, NH);
      float inp = dot_lds(last[q][0], ff1, n, NH);
      float rc  = dot_rec(last[p][1], rec1, n);
      float err = __fsub_rn(inp, pr);
      out[(((size_t)t * 3 + 1) * BATCH + b) * NH + n] = err;
      errsq[1][n] = __fmul_rn(err, err);
      float m1  = __fmul_rn(err, 0.5f);
      float tot = __fadd_rn(__fmaf_rn(m1, prec1, pr), rc);
      float noi = __fmul_rn(0.02f, jax_normal(keys[t][1][0], keys[t][1][1], j));
      v1 = __fadd_rn(__fmaf_rn(DM, v1, tot), noi);
      bool s = (v1 >= 1.0f);
      last[q][1][n] = s ? 1.f : 0.f;
      v1 = s ? 0.f : v1;
    }
    __syncthreads();

    {
      float inp = dot_lds(last[q][1], ff2, n, NH);
      float rc  = dot_rec(last[p][2], rec2, n);
      float err = inp;
      out[(((size_t)t * 3 + 2) * BATCH + b) * NH + n] = err;
      errsq[2][n] = __fmul_rn(err, err);
      float m1  = __fmul_rn(err, 0.5f);
      float tot = __fadd_rn(__fmaf_rn(m1, prec2, 0.0f), rc);
      float noi = __fmul_rn(0.02f, jax_normal(keys[t][2][0], keys[t][2][1], j));
      v2 = __fadd_rn(__fmaf_rn(DM, v2, tot), noi);
      bool s = (v2 >= 1.0f);
      last[q][2][n] = s ? 1.f : 0.f;
      v2 = s ? 0.f : v2;
    }
    __syncthreads();

    if (((n & 63) == 0) && n < 192) {
      const float* s = errsq[n >> 6];
      float acc = 0.f;
      #pragma unroll 32
      for (int k = 0; k < NH; ++k) acc = __fadd_rn(acc, s[k]);
      evsum[n >> 6] = acc;
    }
    __syncthreads();

    {
      float ev0 = __fadd_rn(__fmul_rn(evsum[0], 0.00390625f), 1e-6f);
      float ev1 = __fadd_rn(__fmul_rn(evsum[1], 0.00390625f), 1e-6f);
      float ev2 = __fadd_rn(__fmul_rn(evsum[2], 0.00390625f), 1e-6f);
      prec0 = __fmaf_rn(0.98f, prec0, __fmul_rn(0.02f, 1.0f / ev0));
      prec1 = __fmaf_rn(0.98f, prec1, __fmul_rn(0.02f, 1.0f / ev1));
      prec2 = __fmaf_rn(0.98f, prec2, __fmul_rn(0.02f, 1.0f / ev2));
    }
  }
}

extern "C" void kernel_launch(void* const* d_in, const int* in_sizes, int n_in,
                              void* d_out, int out_size, void* d_ws, size_t ws_size,
                              hipStream_t stream) {
  (void)in_sizes; (void)n_in; (void)out_size;
  const float* sensory = (const float*)d_in[0];
  const float* ff0  = (const float*)d_in[1];
  const float* ff1  = (const float*)d_in[2];
  const float* ff2  = (const float*)d_in[3];
  const float* rec0 = (const float*)d_in[4];
  const float* rec1 = (const float*)d_in[5];
  const float* rec2 = (const float*)d_in[6];
  const float* pred0 = (const float*)d_in[7];
  const float* pred1 = (const float*)d_in[8];
  const float* p2r0 = (const float*)d_in[9];
  const float* p2r1 = (const float*)d_in[10];
  float* out = (float*)d_out;

  // ws layout (floats): packed weights then noise.
  const size_t OFF_PRED0 = 0, OFF_PRED1 = 65536, OFF_P2R0 = 131072,
               OFF_REC0 = 196608, OFF_FF0 = 262144, OFF_P2R1 = 294912,
               OFF_FF1 = 360448, OFF_REC1 = 425984, OFF_FF2 = 491520,
               OFF_REC2 = 557056, OFF_NZ = 655360;
  const size_t NZ_FLOATS = (size_t)TSTEPS * 5 * BATCH * NH;  // 65,536,000
  const size_t NEED = (OFF_NZ + NZ_FLOATS) * sizeof(float);

  if (ws_size >= NEED) {
    float* W = (float*)d_ws;
    pack_w<<<dim3(NH * NH / 256), dim3(256), 0, stream>>>(pred0, W + OFF_PRED0, NH, 0);
    pack_w<<<dim3(NH * NH / 256), dim3(256), 0, stream>>>(pred1, W + OFF_PRED1, NH, 0);
    pack_w<<<dim3(NH * NH / 256), dim3(256), 0, stream>>>(p2r0,  W + OFF_P2R0,  NH, 0);
    pack_w<<<dim3(NH * NH / 256), dim3(256), 0, stream>>>(rec0,  W + OFF_REC0,  NH, 1);
    pack_w<<<dim3(NS * NH / 256), dim3(256), 0, stream>>>(ff0,   W + OFF_FF0,   NS, 0);
    pack_w<<<dim3(NH * NH / 256), dim3(256), 0, stream>>>(p2r1,  W + OFF_P2R1,  NH, 0);
    pack_w<<<dim3(NH * NH / 256), dim3(256), 0, stream>>>(ff1,   W + OFF_FF1,   NH, 0);
    pack_w<<<dim3(NH * NH / 256), dim3(256), 0, stream>>>(rec1,  W + OFF_REC1,  NH, 1);
    pack_w<<<dim3(NH * NH / 256), dim3(256), 0, stream>>>(ff2,   W + OFF_FF2,   NH, 0);
    pack_w<<<dim3(NH * NH / 256), dim3(256), 0, stream>>>(rec2,  W + OFF_REC2,  NH, 1);
    gen_noise<<<dim3((unsigned)(NZ_FLOATS / 256)), dim3(256), 0, stream>>>(W + OFF_NZ);
    wm_fast8<<<dim3(BATCH / 2), dim3(512), 0, stream>>>(
        sensory,
        (const float4*)(W + OFF_PRED0), (const float4*)(W + OFF_PRED1),
        (const float4*)(W + OFF_P2R0),  (const float4*)(W + OFF_REC0),
        (const float4*)(W + OFF_FF0),   (const float4*)(W + OFF_P2R1),
        (const float4*)(W + OFF_FF1),   (const float4*)(W + OFF_REC1),
        (const float4*)(W + OFF_FF2),   (const float4*)(W + OFF_REC2),
        W + OFF_NZ, out);
  } else {
    wm_kernel_mono<<<dim3(BATCH), dim3(NH), 0, stream>>>(
        sensory, ff0, ff1, ff2, rec0, rec1, rec2,
        pred0, pred1, p2r0, p2r1, out);
  }
}